// Round 1
// baseline (44652.118 us; speedup 1.0000x reference)
//
#include <hip/hip_runtime.h>
#include <hip/hip_bf16.h>
#include <math.h>

#define B_ 2
#define L_ 2048
#define D_ 1024
#define VOCAB_ 65536
#define TOOLV_ 128
#define NCONV_ 10
#define NATTN_ 6
#define HEADS_ 8
#define HD_ 128
#define EPS_ 1e-5f

// ---------------- Julia feats + projection ----------------
__global__ __launch_bounds__(256) void julia_proj_k(const float* __restrict__ cs,
    const float* __restrict__ pw, const float* __restrict__ esc, float* __restrict__ h) {
  int row = blockIdx.x;                       // b*L + l
  float cr = cs[2*(size_t)row], ci = cs[2*(size_t)row+1];
  float f[16];
  float zr = 0.f, zi = 0.f;
  #pragma unroll
  for (int s = 0; s < 8; ++s) {
    float nzr = zr*zr - zi*zi + cr;
    float nzi = 2.f*zr*zi + ci;
    zr = nzr; zi = nzi;
    f[2*s] = zr; f[2*s+1] = zi;
  }
  float e = esc[0];
  for (int d = threadIdx.x; d < D_; d += 256) {
    float acc = 0.f;
    #pragma unroll
    for (int i = 0; i < 16; ++i) acc += f[i]*pw[i*D_ + d];
    h[(size_t)row*D_ + d] = acc*e;
  }
}

// ---------------- depthwise conv over L (K=5, zero pad 2) ----------------
__global__ __launch_bounds__(256) void dwconv_k(const float* __restrict__ x,
    const float* __restrict__ w, const float* __restrict__ bias, float* __restrict__ y) {
  size_t idx = (size_t)blockIdx.x*256 + threadIdx.x;   // over B*L*D
  int d = (int)(idx & (D_-1));
  size_t bl = idx >> 10;
  int l = (int)(bl & (L_-1));
  size_t bbase = (bl >> 11) * (size_t)L_;              // b*L
  float acc = bias[d];
  #pragma unroll
  for (int k = 0; k < 5; ++k) {
    int ll = l + k - 2;
    if (ll >= 0 && ll < L_)
      acc += x[(bbase + ll)*D_ + d] * w[d*5 + k];
  }
  y[idx] = acc;
}

// ---------------- tiled fp32 GEMM: C[m,n] = sum_k A[m,k]*B'[k,n] (+bias[n]) ----
// BT=true : B stored (N,K) row-major (i.e. B[n*K+k])
// BT=false: B stored (K,N) row-major (i.e. B[k*N+n])
template<bool BT, bool BIAS>
__global__ __launch_bounds__(256) void gemm_f32(const float* __restrict__ A,
    const float* __restrict__ Bm, const float* __restrict__ bias,
    float* __restrict__ C, int M, int N, int K) {
  __shared__ float As[16][65];
  __shared__ float Bs[16][65];
  int tid = threadIdx.x;
  int tx = tid & 15, ty = tid >> 4;
  int m0 = blockIdx.x * 64, n0 = blockIdx.y * 64;
  float acc[4][4] = {};
  for (int k0 = 0; k0 < K; k0 += 16) {
    {
      int li = tid*4, am = li >> 4, ak = li & 15;
      float4 v = *(const float4*)(A + (size_t)(m0+am)*K + k0 + ak);
      As[ak][am] = v.x; As[ak+1][am] = v.y; As[ak+2][am] = v.z; As[ak+3][am] = v.w;
    }
    if (BT) {
      int li = tid*4, bn = li >> 4, bk = li & 15;
      float4 v = *(const float4*)(Bm + (size_t)(n0+bn)*K + k0 + bk);
      Bs[bk][bn] = v.x; Bs[bk+1][bn] = v.y; Bs[bk+2][bn] = v.z; Bs[bk+3][bn] = v.w;
    } else {
      int li = tid*4, bk = li >> 6, bn = li & 63;
      float4 v = *(const float4*)(Bm + (size_t)(k0+bk)*N + n0 + bn);
      Bs[bk][bn] = v.x; Bs[bk][bn+1] = v.y; Bs[bk][bn+2] = v.z; Bs[bk][bn+3] = v.w;
    }
    __syncthreads();
    #pragma unroll
    for (int kk = 0; kk < 16; ++kk) {
      float a[4], b[4];
      #pragma unroll
      for (int i = 0; i < 4; ++i) a[i] = As[kk][ty*4+i];
      #pragma unroll
      for (int j = 0; j < 4; ++j) b[j] = Bs[kk][tx*4+j];
      #pragma unroll
      for (int i = 0; i < 4; ++i)
        #pragma unroll
        for (int j = 0; j < 4; ++j) acc[i][j] += a[i]*b[j];
    }
    __syncthreads();
  }
  #pragma unroll
  for (int i = 0; i < 4; ++i) {
    int m = m0 + ty*4 + i, n = n0 + tx*4;
    float4 v;
    v.x = acc[i][0]; v.y = acc[i][1]; v.z = acc[i][2]; v.w = acc[i][3];
    if (BIAS) { v.x += bias[n]; v.y += bias[n+1]; v.z += bias[n+2]; v.w += bias[n+3]; }
    *(float4*)(C + (size_t)m*N + n) = v;
  }
}

// ---------------- GLU + residual + LayerNorm (in-place on h) ----------------
__global__ __launch_bounds__(256) void glu_ln_k(float* __restrict__ h,
    const float* __restrict__ y2, const float* __restrict__ s, const float* __restrict__ b) {
  int row = blockIdx.x;
  int tid = threadIdx.x;
  float* xr = h + (size_t)row*D_;
  const float* yr = y2 + (size_t)row*2*D_;
  __shared__ float t[D_];
  __shared__ float red[256];
  float ls = 0.f;
  for (int d = tid; d < D_; d += 256) {
    float a = yr[d], g = yr[D_ + d];
    float sg = 1.f/(1.f + expf(-g));
    float v = xr[d] + a*sg;
    t[d] = v; ls += v;
  }
  red[tid] = ls; __syncthreads();
  for (int st = 128; st > 0; st >>= 1) { if (tid < st) red[tid] += red[tid+st]; __syncthreads(); }
  float mu = red[0] * (1.f/D_); __syncthreads();
  float lv = 0.f;
  for (int d = tid; d < D_; d += 256) { float dd = t[d]-mu; lv += dd*dd; }
  red[tid] = lv; __syncthreads();
  for (int st = 128; st > 0; st >>= 1) { if (tid < st) red[tid] += red[tid+st]; __syncthreads(); }
  float var = red[0] * (1.f/D_);
  float r = 1.f/sqrtf(var + EPS_);
  for (int d = tid; d < D_; d += 256)
    xr[d] = (t[d]-mu)*r*s[d] + b[d];
}

// ---------------- residual + LayerNorm (attention epilogue, in-place) --------
__global__ __launch_bounds__(256) void resid_ln_k(float* __restrict__ h,
    const float* __restrict__ proj, const float* __restrict__ s, const float* __restrict__ b) {
  int row = blockIdx.x;
  int tid = threadIdx.x;
  float* xr = h + (size_t)row*D_;
  const float* pr = proj + (size_t)row*D_;
  __shared__ float t[D_];
  __shared__ float red[256];
  float ls = 0.f;
  for (int d = tid; d < D_; d += 256) { float v = xr[d] + pr[d]; t[d] = v; ls += v; }
  red[tid] = ls; __syncthreads();
  for (int st = 128; st > 0; st >>= 1) { if (tid < st) red[tid] += red[tid+st]; __syncthreads(); }
  float mu = red[0] * (1.f/D_); __syncthreads();
  float lv = 0.f;
  for (int d = tid; d < D_; d += 256) { float dd = t[d]-mu; lv += dd*dd; }
  red[tid] = lv; __syncthreads();
  for (int st = 128; st > 0; st >>= 1) { if (tid < st) red[tid] += red[tid+st]; __syncthreads(); }
  float var = red[0] * (1.f/D_);
  float r = 1.f/sqrtf(var + EPS_);
  for (int d = tid; d < D_; d += 256)
    xr[d] = (t[d]-mu)*r*s[d] + b[d];
}

// ---------------- attention: one block per (b, head, q-row) ------------------
// q buffer (B,L,1024) laid out [b,l,hh*128+d]; kv (B,L,2048) [b,l,hh*256 + j*128 + d]
// out written in-place over the q row.
__global__ __launch_bounds__(128) void attn_k(float* __restrict__ q,
    const float* __restrict__ kv) {
  int qpos = blockIdx.x, hh = blockIdx.y, b = blockIdx.z;
  int tid = threadIdx.x;  // 128
  __shared__ float qs[HD_];
  __shared__ float p[L_];
  __shared__ float red[128];
  float* qrow = q + ((size_t)b*L_ + qpos)*D_ + hh*HD_;
  qs[tid] = qrow[tid];
  __syncthreads();
  const float* kvb = kv + (size_t)b*L_*2048 + hh*256;
  const float scale = 0.088388347648318447f;  // 128^-0.5
  float sv[16];
  float smax = -INFINITY;
  const float4* q4 = (const float4*)qs;
  #pragma unroll 1
  for (int j = 0; j < 16; ++j) {
    int kpos = tid + j*128;
    const float4* k4 = (const float4*)(kvb + (size_t)kpos*2048);
    float acc = 0.f;
    #pragma unroll
    for (int d = 0; d < 32; ++d) {
      float4 kk = k4[d], qq = q4[d];
      acc += qq.x*kk.x + qq.y*kk.y + qq.z*kk.z + qq.w*kk.w;
    }
    acc *= scale;
    sv[j] = acc;
    smax = fmaxf(smax, acc);
  }
  red[tid] = smax; __syncthreads();
  for (int st = 64; st > 0; st >>= 1) { if (tid < st) red[tid] = fmaxf(red[tid], red[tid+st]); __syncthreads(); }
  float m = red[0]; __syncthreads();
  float lsum = 0.f;
  #pragma unroll
  for (int j = 0; j < 16; ++j) {
    float e = expf(sv[j] - m);
    p[tid + j*128] = e;
    lsum += e;
  }
  red[tid] = lsum; __syncthreads();
  for (int st = 64; st > 0; st >>= 1) { if (tid < st) red[tid] += red[tid+st]; __syncthreads(); }
  float inv = 1.f/red[0];
  __syncthreads();
  const float* vb = kvb + 128;
  float acc = 0.f;
  for (int k = 0; k < L_; k += 8) {
    #pragma unroll
    for (int u = 0; u < 8; ++u)
      acc += p[k+u] * vb[(size_t)(k+u)*2048 + tid];
  }
  qrow[tid] = acc * inv;
}

// ---------------- heads ----------------
__global__ __launch_bounds__(256) void lm_head_k(const float* __restrict__ h,
    const float* __restrict__ lm_w, float* __restrict__ out) {
  int tid = threadIdx.x;
  int n = blockIdx.x*256 + tid;
  __shared__ float last0[D_], last1[D_];
  const float* h0 = h + ((size_t)0*L_ + (L_-1))*D_;
  const float* h1 = h + ((size_t)1*L_ + (L_-1))*D_;
  for (int d = tid; d < D_; d += 256) { last0[d] = h0[d]; last1[d] = h1[d]; }
  __syncthreads();
  float a0 = 0.f, a1 = 0.f;
  for (int k = 0; k < D_; ++k) {
    float w = lm_w[(size_t)k*VOCAB_ + n];
    a0 += last0[k]*w; a1 += last1[k]*w;
  }
  out[n] = a0;
  out[(size_t)VOCAB_ + n] = a1;
}

__global__ __launch_bounds__(128) void tool_head_k(const float* __restrict__ h,
    const float* __restrict__ tw, const float* __restrict__ tb, float* __restrict__ out) {
  int b = blockIdx.x;
  int tid = threadIdx.x;  // 128
  __shared__ float last[D_];
  const float* hr = h + ((size_t)b*L_ + (L_-1))*D_;
  for (int d = tid; d < D_; d += 128) last[d] = hr[d];
  __syncthreads();
  float acc = tb[tid];
  for (int k = 0; k < D_; ++k) acc += last[k]*tw[(size_t)k*TOOLV_ + tid];
  out[(size_t)2*VOCAB_ + (size_t)b*TOOLV_ + tid] = acc;
}

extern "C" void kernel_launch(void* const* d_in, const int* in_sizes, int n_in,
                              void* d_out, int out_size, void* d_ws, size_t ws_size,
                              hipStream_t stream) {
  const float* cs        = (const float*)d_in[1];
  const float* proj_w    = (const float*)d_in[2];
  const float* emb_scale = (const float*)d_in[3];
  const float* conv_dw_w = (const float*)d_in[4];
  const float* conv_dw_b = (const float*)d_in[5];
  const float* conv_pw_w = (const float*)d_in[6];
  const float* conv_pw_b = (const float*)d_in[7];
  const float* conv_ln_s = (const float*)d_in[8];
  const float* conv_ln_b = (const float*)d_in[9];
  const float* attn_q_w  = (const float*)d_in[10];
  const float* attn_kv_w = (const float*)d_in[11];
  const float* attn_out_w= (const float*)d_in[12];
  const float* attn_ln_s = (const float*)d_in[13];
  const float* attn_ln_b = (const float*)d_in[14];
  const float* lm_w      = (const float*)d_in[15];
  const float* tool_w    = (const float*)d_in[16];
  const float* tool_b    = (const float*)d_in[17];

  float* h    = (float*)d_ws;                       // B*L*D
  float* buf2 = h    + (size_t)B_*L_*D_;            // B*L*2D
  float* buf1 = buf2 + (size_t)B_*L_*2*D_;          // B*L*D

  const int M = B_*L_;

  julia_proj_k<<<B_*L_, 256, 0, stream>>>(cs, proj_w, emb_scale, h);

  for (int i = 0; i < NCONV_; ++i) {
    dwconv_k<<<(B_*L_*D_)/256, 256, 0, stream>>>(h, conv_dw_w + (size_t)i*D_*5,
                                                 conv_dw_b + (size_t)i*D_, buf1);
    gemm_f32<true, true><<<dim3(M/64, (2*D_)/64), 256, 0, stream>>>(
        buf1, conv_pw_w + (size_t)i*2*D_*D_, conv_pw_b + (size_t)i*2*D_,
        buf2, M, 2*D_, D_);
    glu_ln_k<<<B_*L_, 256, 0, stream>>>(h, buf2, conv_ln_s + (size_t)i*D_,
                                        conv_ln_b + (size_t)i*D_);
  }

  for (int i = 0; i < NATTN_; ++i) {
    gemm_f32<false, false><<<dim3(M/64, D_/64), 256, 0, stream>>>(
        h, attn_q_w + (size_t)i*D_*D_, nullptr, buf1, M, D_, D_);
    gemm_f32<false, false><<<dim3(M/64, (2*D_)/64), 256, 0, stream>>>(
        h, attn_kv_w + (size_t)i*D_*2*D_, nullptr, buf2, M, 2*D_, D_);
    attn_k<<<dim3(L_, HEADS_, B_), 128, 0, stream>>>(buf1, buf2);
    gemm_f32<false, false><<<dim3(M/64, D_/64), 256, 0, stream>>>(
        buf1, attn_out_w + (size_t)i*D_*D_, nullptr, buf2, M, D_, D_);
    resid_ln_k<<<B_*L_, 256, 0, stream>>>(h, buf2, attn_ln_s + (size_t)i*D_,
                                          attn_ln_b + (size_t)i*D_);
  }

  lm_head_k<<<dim3(VOCAB_/256, 1), 256, 0, stream>>>(h, lm_w, (float*)d_out);
  tool_head_k<<<B_, 128, 0, stream>>>(h, tool_w, tool_b, (float*)d_out);
}

// Round 2
// 8995.242 us; speedup vs baseline: 4.9640x; 4.9640x over previous
//
#include <hip/hip_runtime.h>
#include <hip/hip_bf16.h>
#include <math.h>

#define B_ 2
#define L_ 2048
#define D_ 1024
#define VOCAB_ 65536
#define TOOLV_ 128
#define NCONV_ 10
#define NATTN_ 6
#define HEADS_ 8
#define HD_ 128
#define EPS_ 1e-5f

typedef short bf16x8 __attribute__((ext_vector_type(8)));
typedef short short4v __attribute__((ext_vector_type(4)));
typedef float f32x4 __attribute__((ext_vector_type(4)));
#define MFMA16(a,b,c) __builtin_amdgcn_mfma_f32_16x16x32_bf16(a, b, c, 0, 0, 0)

__device__ inline short f2bf(float f) {
  __hip_bfloat16 h = __float2bfloat16(f);
  return *reinterpret_cast<short*>(&h);
}

// ---------------- Julia feats + projection ----------------
__global__ __launch_bounds__(256) void julia_proj_k(const float* __restrict__ cs,
    const float* __restrict__ pw, const float* __restrict__ esc, float* __restrict__ h) {
  int row = blockIdx.x;                       // b*L + l
  float cr = cs[2*(size_t)row], ci = cs[2*(size_t)row+1];
  float f[16];
  float zr = 0.f, zi = 0.f;
  #pragma unroll
  for (int s = 0; s < 8; ++s) {
    float nzr = zr*zr - zi*zi + cr;
    float nzi = 2.f*zr*zi + ci;
    zr = nzr; zi = nzi;
    f[2*s] = zr; f[2*s+1] = zi;
  }
  float e = esc[0];
  for (int d = threadIdx.x; d < D_; d += 256) {
    float acc = 0.f;
    #pragma unroll
    for (int i = 0; i < 16; ++i) acc += f[i]*pw[i*D_ + d];
    h[(size_t)row*D_ + d] = acc*e;
  }
}

// ---------------- depthwise conv over L (K=5, zero pad 2) ----------------
__global__ __launch_bounds__(256) void dwconv_k(const float* __restrict__ x,
    const float* __restrict__ w, const float* __restrict__ bias, float* __restrict__ y) {
  size_t idx = (size_t)blockIdx.x*256 + threadIdx.x;   // over B*L*D
  int d = (int)(idx & (D_-1));
  size_t bl = idx >> 10;
  int l = (int)(bl & (L_-1));
  size_t bbase = (bl >> 11) * (size_t)L_;              // b*L
  float acc = bias[d];
  #pragma unroll
  for (int k = 0; k < 5; ++k) {
    int ll = l + k - 2;
    if (ll >= 0 && ll < L_)
      acc += x[(bbase + ll)*D_ + d] * w[d*5 + k];
  }
  y[idx] = acc;
}

// ---------------- tiled fp32 GEMM ----------
template<bool BT, bool BIAS>
__global__ __launch_bounds__(256) void gemm_f32(const float* __restrict__ A,
    const float* __restrict__ Bm, const float* __restrict__ bias,
    float* __restrict__ C, int M, int N, int K) {
  __shared__ float As[16][65];
  __shared__ float Bs[16][65];
  int tid = threadIdx.x;
  int tx = tid & 15, ty = tid >> 4;
  int m0 = blockIdx.x * 64, n0 = blockIdx.y * 64;
  float acc[4][4] = {};
  for (int k0 = 0; k0 < K; k0 += 16) {
    {
      int li = tid*4, am = li >> 4, ak = li & 15;
      float4 v = *(const float4*)(A + (size_t)(m0+am)*K + k0 + ak);
      As[ak][am] = v.x; As[ak+1][am] = v.y; As[ak+2][am] = v.z; As[ak+3][am] = v.w;
    }
    if (BT) {
      int li = tid*4, bn = li >> 4, bk = li & 15;
      float4 v = *(const float4*)(Bm + (size_t)(n0+bn)*K + k0 + bk);
      Bs[bk][bn] = v.x; Bs[bk+1][bn] = v.y; Bs[bk+2][bn] = v.z; Bs[bk+3][bn] = v.w;
    } else {
      int li = tid*4, bk = li >> 6, bn = li & 63;
      float4 v = *(const float4*)(Bm + (size_t)(k0+bk)*N + n0 + bn);
      Bs[bk][bn] = v.x; Bs[bk][bn+1] = v.y; Bs[bk][bn+2] = v.z; Bs[bk][bn+3] = v.w;
    }
    __syncthreads();
    #pragma unroll
    for (int kk = 0; kk < 16; ++kk) {
      float a[4], b[4];
      #pragma unroll
      for (int i = 0; i < 4; ++i) a[i] = As[kk][ty*4+i];
      #pragma unroll
      for (int j = 0; j < 4; ++j) b[j] = Bs[kk][tx*4+j];
      #pragma unroll
      for (int i = 0; i < 4; ++i)
        #pragma unroll
        for (int j = 0; j < 4; ++j) acc[i][j] += a[i]*b[j];
    }
    __syncthreads();
  }
  #pragma unroll
  for (int i = 0; i < 4; ++i) {
    int m = m0 + ty*4 + i, n = n0 + tx*4;
    float4 v;
    v.x = acc[i][0]; v.y = acc[i][1]; v.z = acc[i][2]; v.w = acc[i][3];
    if (BIAS) { v.x += bias[n]; v.y += bias[n+1]; v.z += bias[n+2]; v.w += bias[n+3]; }
    *(float4*)(C + (size_t)m*N + n) = v;
  }
}

// ---------------- GLU + residual + LayerNorm (in-place on h) ----------------
__global__ __launch_bounds__(256) void glu_ln_k(float* __restrict__ h,
    const float* __restrict__ y2, const float* __restrict__ s, const float* __restrict__ b) {
  int row = blockIdx.x;
  int tid = threadIdx.x;
  float* xr = h + (size_t)row*D_;
  const float* yr = y2 + (size_t)row*2*D_;
  __shared__ float t[D_];
  __shared__ float red[256];
  float ls = 0.f;
  for (int d = tid; d < D_; d += 256) {
    float a = yr[d], g = yr[D_ + d];
    float sg = 1.f/(1.f + expf(-g));
    float v = xr[d] + a*sg;
    t[d] = v; ls += v;
  }
  red[tid] = ls; __syncthreads();
  for (int st = 128; st > 0; st >>= 1) { if (tid < st) red[tid] += red[tid+st]; __syncthreads(); }
  float mu = red[0] * (1.f/D_); __syncthreads();
  float lv = 0.f;
  for (int d = tid; d < D_; d += 256) { float dd = t[d]-mu; lv += dd*dd; }
  red[tid] = lv; __syncthreads();
  for (int st = 128; st > 0; st >>= 1) { if (tid < st) red[tid] += red[tid+st]; __syncthreads(); }
  float var = red[0] * (1.f/D_);
  float r = 1.f/sqrtf(var + EPS_);
  for (int d = tid; d < D_; d += 256)
    xr[d] = (t[d]-mu)*r*s[d] + b[d];
}

// ---------------- residual + LayerNorm (attention epilogue, in-place) --------
__global__ __launch_bounds__(256) void resid_ln_k(float* __restrict__ h,
    const float* __restrict__ proj, const float* __restrict__ s, const float* __restrict__ b) {
  int row = blockIdx.x;
  int tid = threadIdx.x;
  float* xr = h + (size_t)row*D_;
  const float* pr = proj + (size_t)row*D_;
  __shared__ float t[D_];
  __shared__ float red[256];
  float ls = 0.f;
  for (int d = tid; d < D_; d += 256) { float v = xr[d] + pr[d]; t[d] = v; ls += v; }
  red[tid] = ls; __syncthreads();
  for (int st = 128; st > 0; st >>= 1) { if (tid < st) red[tid] += red[tid+st]; __syncthreads(); }
  float mu = red[0] * (1.f/D_); __syncthreads();
  float lv = 0.f;
  for (int d = tid; d < D_; d += 256) { float dd = t[d]-mu; lv += dd*dd; }
  red[tid] = lv; __syncthreads();
  for (int st = 128; st > 0; st >>= 1) { if (tid < st) red[tid] += red[tid+st]; __syncthreads(); }
  float var = red[0] * (1.f/D_);
  float r = 1.f/sqrtf(var + EPS_);
  for (int d = tid; d < D_; d += 256)
    xr[d] = (t[d]-mu)*r*s[d] + b[d];
}

// ---------------- flash attention, bf16 MFMA ------------------
// grid (L/64, HEADS, B), block 256 (4 waves). Wave w owns q rows [q0+16w, +16).
// q buffer fp32 (B,L,1024) [b,l,hh*128+d]; kv fp32 (B,L,2048) [b,l,hh*256+j*128+d].
// Result written in place over the q rows.
#define KPITCH 136
#define VPITCH 140
#define PPITCH 72
__global__ __launch_bounds__(256) void attn_mfma_k(float* __restrict__ q,
    const float* __restrict__ kv) {
  __shared__ short Ks[64*KPITCH];
  __shared__ short Vs[64*VPITCH];
  __shared__ short Ps[4*16*PPITCH];

  const int tid  = threadIdx.x;
  const int wave = tid >> 6;
  const int lane = tid & 63;
  const int g    = lane >> 4;      // lane group 0..3
  const int c    = lane & 15;      // low lane index
  const int hh   = blockIdx.y;
  const int b    = blockIdx.z;
  const int q0   = blockIdx.x*64 + wave*16;
  const float scale = 0.088388347648318447f;  // 128^-0.5

  // ---- Q fragments (A-operand): row = c, k = kd*32 + g*8 + i ----
  bf16x8 qf[4];
  {
    const float* Qp = q + ((size_t)(b*L_ + q0 + c))*D_ + hh*HD_;
    #pragma unroll
    for (int kd = 0; kd < 4; ++kd) {
      int base = kd*32 + g*8;
      #pragma unroll
      for (int i = 0; i < 8; ++i) qf[kd][i] = f2bf(Qp[base + i]);
    }
  }

  f32x4 O[8];
  #pragma unroll
  for (int i = 0; i < 8; ++i) O[i] = (f32x4){0.f,0.f,0.f,0.f};
  float mrun[4] = {-INFINITY,-INFINITY,-INFINITY,-INFINITY};
  float lrun[4] = {0.f,0.f,0.f,0.f};

  short* Pw = Ps + wave*16*PPITCH;
  const int kr = tid >> 2;            // staging row 0..63
  const int d0 = (tid & 3) * 32;      // staging col base

  for (int t = 0; t < L_/64; ++t) {
    __syncthreads();   // previous tile fully consumed
    // ---- stage K,V (fp32 -> bf16) ----
    {
      const float* Krow = kv + ((size_t)(b*L_ + t*64 + kr))*2048 + hh*256;
      const float* Vrow = Krow + HD_;
      #pragma unroll
      for (int j = 0; j < 8; ++j) {
        float4 kk = *(const float4*)(Krow + d0 + j*4);
        float4 vv = *(const float4*)(Vrow + d0 + j*4);
        short4v ks4 = { f2bf(kk.x), f2bf(kk.y), f2bf(kk.z), f2bf(kk.w) };
        short4v vs4 = { f2bf(vv.x), f2bf(vv.y), f2bf(vv.z), f2bf(vv.w) };
        *(short4v*)&Ks[kr*KPITCH + d0 + j*4] = ks4;
        *(short4v*)&Vs[kr*VPITCH + d0 + j*4] = vs4;
      }
    }
    __syncthreads();

    // ---- S = Q K^T (scaled) : 4 col-chunks of 16 kv positions ----
    f32x4 s[4];
    #pragma unroll
    for (int nc = 0; nc < 4; ++nc) {
      s[nc] = (f32x4){0.f,0.f,0.f,0.f};
      #pragma unroll
      for (int kd = 0; kd < 4; ++kd) {
        bf16x8 kf = *(const bf16x8*)&Ks[(nc*16 + c)*KPITCH + kd*32 + g*8];
        s[nc] = MFMA16(qf[kd], kf, s[nc]);
      }
      #pragma unroll
      for (int r = 0; r < 4; ++r) s[nc][r] *= scale;
    }

    // ---- online softmax (rows g*4+r, cols spread over 16 lanes x 4 chunks) ----
    float tm[4], rsum[4], alpha[4];
    #pragma unroll
    for (int r = 0; r < 4; ++r) {
      tm[r] = fmaxf(fmaxf(s[0][r], s[1][r]), fmaxf(s[2][r], s[3][r]));
    }
    #pragma unroll
    for (int r = 0; r < 4; ++r) {
      #pragma unroll
      for (int mask = 1; mask <= 8; mask <<= 1)
        tm[r] = fmaxf(tm[r], __shfl_xor(tm[r], mask));
      float mnew = fmaxf(mrun[r], tm[r]);
      alpha[r] = expf(mrun[r] - mnew);
      mrun[r] = mnew;
      rsum[r] = 0.f;
    }
    #pragma unroll
    for (int nc = 0; nc < 4; ++nc)
      #pragma unroll
      for (int r = 0; r < 4; ++r) {
        float p = expf(s[nc][r] - mrun[r]);
        s[nc][r] = p;
        rsum[r] += p;
      }
    #pragma unroll
    for (int r = 0; r < 4; ++r) {
      #pragma unroll
      for (int mask = 1; mask <= 8; mask <<= 1)
        rsum[r] += __shfl_xor(rsum[r], mask);
      lrun[r] = lrun[r]*alpha[r] + rsum[r];
    }
    #pragma unroll
    for (int nc = 0; nc < 8; ++nc)
      #pragma unroll
      for (int r = 0; r < 4; ++r) O[nc][r] *= alpha[r];

    // ---- P -> bf16 via per-wave LDS (re-layout to A-fragments) ----
    #pragma unroll
    for (int nc = 0; nc < 4; ++nc)
      #pragma unroll
      for (int r = 0; r < 4; ++r)
        Pw[(g*4+r)*PPITCH + nc*16 + c] = f2bf(s[nc][r]);
    asm volatile("s_waitcnt lgkmcnt(0)" ::: "memory");
    bf16x8 pa0 = *(const bf16x8*)&Pw[c*PPITCH + g*8];
    bf16x8 pa1 = *(const bf16x8*)&Pw[c*PPITCH + 32 + g*8];

    // ---- O += P V ----
    #pragma unroll
    for (int ks = 0; ks < 2; ++ks) {
      #pragma unroll
      for (int nc = 0; nc < 8; ++nc) {
        bf16x8 vf;
        #pragma unroll
        for (int i = 0; i < 8; ++i)
          vf[i] = Vs[(ks*32 + g*8 + i)*VPITCH + nc*16 + c];
        O[nc] = MFMA16(ks ? pa1 : pa0, vf, O[nc]);
      }
    }
  }

  // ---- epilogue: O / l, write in place ----
  float* op = q + ((size_t)(b*L_ + q0))*D_ + hh*HD_;
  #pragma unroll
  for (int r = 0; r < 4; ++r) {
    float inv = 1.f / lrun[r];
    #pragma unroll
    for (int nc = 0; nc < 8; ++nc)
      op[(size_t)(g*4+r)*D_ + nc*16 + c] = O[nc][r] * inv;
  }
}

// ---------------- heads ----------------
__global__ __launch_bounds__(256) void lm_head_k(const float* __restrict__ h,
    const float* __restrict__ lm_w, float* __restrict__ out) {
  int tid = threadIdx.x;
  int n = blockIdx.x*256 + tid;
  __shared__ float last0[D_], last1[D_];
  const float* h0 = h + ((size_t)0*L_ + (L_-1))*D_;
  const float* h1 = h + ((size_t)1*L_ + (L_-1))*D_;
  for (int d = tid; d < D_; d += 256) { last0[d] = h0[d]; last1[d] = h1[d]; }
  __syncthreads();
  float a0 = 0.f, a1 = 0.f;
  for (int k = 0; k < D_; ++k) {
    float w = lm_w[(size_t)k*VOCAB_ + n];
    a0 += last0[k]*w; a1 += last1[k]*w;
  }
  out[n] = a0;
  out[(size_t)VOCAB_ + n] = a1;
}

__global__ __launch_bounds__(128) void tool_head_k(const float* __restrict__ h,
    const float* __restrict__ tw, const float* __restrict__ tb, float* __restrict__ out) {
  int b = blockIdx.x;
  int tid = threadIdx.x;  // 128
  __shared__ float last[D_];
  const float* hr = h + ((size_t)b*L_ + (L_-1))*D_;
  for (int d = tid; d < D_; d += 128) last[d] = hr[d];
  __syncthreads();
  float acc = tb[tid];
  for (int k = 0; k < D_; ++k) acc += last[k]*tw[(size_t)k*TOOLV_ + tid];
  out[(size_t)2*VOCAB_ + (size_t)b*TOOLV_ + tid] = acc;
}

extern "C" void kernel_launch(void* const* d_in, const int* in_sizes, int n_in,
                              void* d_out, int out_size, void* d_ws, size_t ws_size,
                              hipStream_t stream) {
  const float* cs        = (const float*)d_in[1];
  const float* proj_w    = (const float*)d_in[2];
  const float* emb_scale = (const float*)d_in[3];
  const float* conv_dw_w = (const float*)d_in[4];
  const float* conv_dw_b = (const float*)d_in[5];
  const float* conv_pw_w = (const float*)d_in[6];
  const float* conv_pw_b = (const float*)d_in[7];
  const float* conv_ln_s = (const float*)d_in[8];
  const float* conv_ln_b = (const float*)d_in[9];
  const float* attn_q_w  = (const float*)d_in[10];
  const float* attn_kv_w = (const float*)d_in[11];
  const float* attn_out_w= (const float*)d_in[12];
  const float* attn_ln_s = (const float*)d_in[13];
  const float* attn_ln_b = (const float*)d_in[14];
  const float* lm_w      = (const float*)d_in[15];
  const float* tool_w    = (const float*)d_in[16];
  const float* tool_b    = (const float*)d_in[17];

  float* h    = (float*)d_ws;                       // B*L*D
  float* buf2 = h    + (size_t)B_*L_*D_;            // B*L*2D
  float* buf1 = buf2 + (size_t)B_*L_*2*D_;          // B*L*D

  const int M = B_*L_;

  julia_proj_k<<<B_*L_, 256, 0, stream>>>(cs, proj_w, emb_scale, h);

  for (int i = 0; i < NCONV_; ++i) {
    dwconv_k<<<(B_*L_*D_)/256, 256, 0, stream>>>(h, conv_dw_w + (size_t)i*D_*5,
                                                 conv_dw_b + (size_t)i*D_, buf1);
    gemm_f32<true, true><<<dim3(M/64, (2*D_)/64), 256, 0, stream>>>(
        buf1, conv_pw_w + (size_t)i*2*D_*D_, conv_pw_b + (size_t)i*2*D_,
        buf2, M, 2*D_, D_);
    glu_ln_k<<<B_*L_, 256, 0, stream>>>(h, buf2, conv_ln_s + (size_t)i*D_,
                                        conv_ln_b + (size_t)i*D_);
  }

  for (int i = 0; i < NATTN_; ++i) {
    gemm_f32<false, false><<<dim3(M/64, D_/64), 256, 0, stream>>>(
        h, attn_q_w + (size_t)i*D_*D_, nullptr, buf1, M, D_, D_);
    gemm_f32<false, false><<<dim3(M/64, (2*D_)/64), 256, 0, stream>>>(
        h, attn_kv_w + (size_t)i*D_*2*D_, nullptr, buf2, M, 2*D_, D_);
    attn_mfma_k<<<dim3(L_/64, HEADS_, B_), 256, 0, stream>>>(buf1, buf2);
    gemm_f32<false, false><<<dim3(M/64, D_/64), 256, 0, stream>>>(
        buf1, attn_out_w + (size_t)i*D_*D_, nullptr, buf2, M, D_, D_);
    resid_ln_k<<<B_*L_, 256, 0, stream>>>(h, buf2, attn_ln_s + (size_t)i*D_,
                                          attn_ln_b + (size_t)i*D_);
  }

  lm_head_k<<<dim3(VOCAB_/256, 1), 256, 0, stream>>>(h, lm_w, (float*)d_out);
  tool_head_k<<<B_, 128, 0, stream>>>(h, tool_w, tool_b, (float*)d_out);
}

// Round 3
// 2602.842 us; speedup vs baseline: 17.1551x; 3.4559x over previous
//
#include <hip/hip_runtime.h>
#include <hip/hip_bf16.h>
#include <math.h>

#define B_ 2
#define L_ 2048
#define D_ 1024
#define VOCAB_ 65536
#define TOOLV_ 128
#define NCONV_ 10
#define NATTN_ 6
#define HEADS_ 8
#define HD_ 128
#define EPS_ 1e-5f

typedef short bf16x8 __attribute__((ext_vector_type(8)));
typedef short short4v __attribute__((ext_vector_type(4)));
typedef float f32x4 __attribute__((ext_vector_type(4)));
#define MFMA16(a,b,c) __builtin_amdgcn_mfma_f32_16x16x32_bf16(a, b, c, 0, 0, 0)

__device__ inline short f2bf(float f) {
  __hip_bfloat16 h = __float2bfloat16(f);
  return *reinterpret_cast<short*>(&h);
}

__device__ __forceinline__ void gld16(const void* g, void* l) {
  __builtin_amdgcn_global_load_lds(
      (const __attribute__((address_space(1))) unsigned int*)g,
      (__attribute__((address_space(3))) unsigned int*)l, 16, 0, 0);
}

// ---------------- Julia feats + projection ----------------
__global__ __launch_bounds__(256) void julia_proj_k(const float* __restrict__ cs,
    const float* __restrict__ pw, const float* __restrict__ esc, float* __restrict__ h) {
  int row = blockIdx.x;                       // b*L + l
  float cr = cs[2*(size_t)row], ci = cs[2*(size_t)row+1];
  float f[16];
  float zr = 0.f, zi = 0.f;
  #pragma unroll
  for (int s = 0; s < 8; ++s) {
    float nzr = zr*zr - zi*zi + cr;
    float nzi = 2.f*zr*zi + ci;
    zr = nzr; zi = nzi;
    f[2*s] = zr; f[2*s+1] = zi;
  }
  float e = esc[0];
  for (int d = threadIdx.x; d < D_; d += 256) {
    float acc = 0.f;
    #pragma unroll
    for (int i = 0; i < 16; ++i) acc += f[i]*pw[i*D_ + d];
    h[(size_t)row*D_ + d] = acc*e;
  }
}

// ---------------- depthwise conv over L (K=5, zero pad 2), bf16 out ---------
__global__ __launch_bounds__(256) void dwconv_k(const float* __restrict__ x,
    const float* __restrict__ w, const float* __restrict__ bias, short* __restrict__ y) {
  size_t idx = (size_t)blockIdx.x*256 + threadIdx.x;   // over B*L*D
  int d = (int)(idx & (D_-1));
  size_t bl = idx >> 10;
  int l = (int)(bl & (L_-1));
  size_t bbase = (bl >> 11) * (size_t)L_;              // b*L
  float acc = bias[d];
  #pragma unroll
  for (int k = 0; k < 5; ++k) {
    int ll = l + k - 2;
    if (ll >= 0 && ll < L_)
      acc += x[(bbase + ll)*D_ + d] * w[d*5 + k];
  }
  y[idx] = f2bf(acc);
}

// ---------------- weight converts ----------------
// elementwise fp32 -> bf16 (n multiple of 1024)
__global__ __launch_bounds__(256) void cvt_bf16_k(const float* __restrict__ x,
    short* __restrict__ y) {
  int i = blockIdx.x*256 + threadIdx.x;
  float4 v = ((const float4*)x)[i];
  short4v s = { f2bf(v.x), f2bf(v.y), f2bf(v.z), f2bf(v.w) };
  ((short4v*)y)[i] = s;
}

// (K,N) fp32 -> (N,K) bf16 transpose
__global__ __launch_bounds__(256) void transp_bf16_k(const float* __restrict__ W,
    short* __restrict__ WT, int K, int N) {
  __shared__ short t[32][33];
  int n0 = blockIdx.x*32, k0 = blockIdx.y*32;
  int tx = threadIdx.x & 31, ty = threadIdx.x >> 5;   // ty 0..7
  #pragma unroll
  for (int i = 0; i < 4; ++i) {
    int k = ty + i*8;
    t[tx][k] = f2bf(W[(size_t)(k0+k)*N + n0 + tx]);
  }
  __syncthreads();
  #pragma unroll
  for (int i = 0; i < 4; ++i) {
    int n = ty + i*8;
    WT[(size_t)(n0+n)*K + k0 + tx] = t[n][tx];
  }
}

// ---------------- bf16 MFMA GEMM: C(M,N) fp32 = A(M,K)bf16 x Bt(N,K)bf16 -----
// 128x128 tile, BK=32, 256 threads (2x2 waves), global_load_lds staging.
template<bool BIAS>
__global__ __launch_bounds__(256) void gemm_bf16(const short* __restrict__ A,
    const short* __restrict__ Bt, const float* __restrict__ bias,
    float* __restrict__ C, int M, int N, int K) {
  __shared__ short As[128*32];
  __shared__ short Bs[128*32];
  const int tid  = threadIdx.x;
  const int lane = tid & 63;
  const int wave = tid >> 6;
  const int wm = wave >> 1, wn = wave & 1;
  const int g = lane >> 4, c = lane & 15;
  const int m0 = blockIdx.x * 128, n0 = blockIdx.y * 128;

  f32x4 acc[4][4];
  #pragma unroll
  for (int i = 0; i < 4; ++i)
    #pragma unroll
    for (int j = 0; j < 4; ++j) acc[i][j] = (f32x4){0.f,0.f,0.f,0.f};

  // staging source pointers: round r covers rows r*64 + wave*16 + lane/4
  const int srow = wave*16 + (lane>>2);
  const int scol = (lane&3)*8;
  const short* aSrc0 = A + (size_t)(m0 + srow)*K + scol;
  const short* aSrc1 = aSrc0 + (size_t)64*K;
  const short* bSrc0 = Bt + (size_t)(n0 + srow)*K + scol;
  const short* bSrc1 = bSrc0 + (size_t)64*K;
  short* AsW = &As[wave*512];
  short* BsW = &Bs[wave*512];

  for (int k0 = 0; k0 < K; k0 += 32) {
    __syncthreads();                       // LDS free (prev tile consumed)
    gld16(aSrc0 + k0, AsW);
    gld16(aSrc1 + k0, AsW + 2048);
    gld16(bSrc0 + k0, BsW);
    gld16(bSrc1 + k0, BsW + 2048);
    asm volatile("s_waitcnt vmcnt(0)" ::: "memory");
    __syncthreads();                       // tile visible to all waves

    bf16x8 af[4], bfr[4];
    #pragma unroll
    for (int mi = 0; mi < 4; ++mi)
      af[mi] = *(const bf16x8*)&As[(wm*64 + mi*16 + c)*32 + g*8];
    #pragma unroll
    for (int ni = 0; ni < 4; ++ni)
      bfr[ni] = *(const bf16x8*)&Bs[(wn*64 + ni*16 + c)*32 + g*8];
    #pragma unroll
    for (int mi = 0; mi < 4; ++mi)
      #pragma unroll
      for (int ni = 0; ni < 4; ++ni)
        acc[mi][ni] = MFMA16(af[mi], bfr[ni], acc[mi][ni]);
  }

  #pragma unroll
  for (int mi = 0; mi < 4; ++mi) {
    int row = m0 + wm*64 + mi*16 + g*4;
    #pragma unroll
    for (int ni = 0; ni < 4; ++ni) {
      int col = n0 + wn*64 + ni*16 + c;
      float bv = BIAS ? bias[col] : 0.f;
      #pragma unroll
      for (int r = 0; r < 4; ++r)
        C[(size_t)(row+r)*N + col] = acc[mi][ni][r] + bv;
    }
  }
}

// ---------------- GLU + residual + LayerNorm (in-place on h, opt bf16 out) ---
__global__ __launch_bounds__(256) void glu_ln_k(float* __restrict__ h,
    const float* __restrict__ y2, const float* __restrict__ s, const float* __restrict__ b,
    short* __restrict__ bo) {
  int row = blockIdx.x;
  int tid = threadIdx.x;
  float* xr = h + (size_t)row*D_;
  const float* yr = y2 + (size_t)row*2*D_;
  __shared__ float t[D_];
  __shared__ float red[256];
  float ls = 0.f;
  for (int d = tid; d < D_; d += 256) {
    float a = yr[d], g = yr[D_ + d];
    float sg = 1.f/(1.f + expf(-g));
    float v = xr[d] + a*sg;
    t[d] = v; ls += v;
  }
  red[tid] = ls; __syncthreads();
  for (int st = 128; st > 0; st >>= 1) { if (tid < st) red[tid] += red[tid+st]; __syncthreads(); }
  float mu = red[0] * (1.f/D_); __syncthreads();
  float lv = 0.f;
  for (int d = tid; d < D_; d += 256) { float dd = t[d]-mu; lv += dd*dd; }
  red[tid] = lv; __syncthreads();
  for (int st = 128; st > 0; st >>= 1) { if (tid < st) red[tid] += red[tid+st]; __syncthreads(); }
  float var = red[0] * (1.f/D_);
  float r = 1.f/sqrtf(var + EPS_);
  for (int d = tid; d < D_; d += 256) {
    float v = (t[d]-mu)*r*s[d] + b[d];
    xr[d] = v;
    if (bo) bo[(size_t)row*D_ + d] = f2bf(v);
  }
}

// ---------------- residual + LayerNorm (attention epilogue, opt bf16 out) ----
__global__ __launch_bounds__(256) void resid_ln_k(float* __restrict__ h,
    const float* __restrict__ proj, const float* __restrict__ s, const float* __restrict__ b,
    short* __restrict__ bo) {
  int row = blockIdx.x;
  int tid = threadIdx.x;
  float* xr = h + (size_t)row*D_;
  const float* pr = proj + (size_t)row*D_;
  __shared__ float t[D_];
  __shared__ float red[256];
  float ls = 0.f;
  for (int d = tid; d < D_; d += 256) { float v = xr[d] + pr[d]; t[d] = v; ls += v; }
  red[tid] = ls; __syncthreads();
  for (int st = 128; st > 0; st >>= 1) { if (tid < st) red[tid] += red[tid+st]; __syncthreads(); }
  float mu = red[0] * (1.f/D_); __syncthreads();
  float lv = 0.f;
  for (int d = tid; d < D_; d += 256) { float dd = t[d]-mu; lv += dd*dd; }
  red[tid] = lv; __syncthreads();
  for (int st = 128; st > 0; st >>= 1) { if (tid < st) red[tid] += red[tid+st]; __syncthreads(); }
  float var = red[0] * (1.f/D_);
  float r = 1.f/sqrtf(var + EPS_);
  for (int d = tid; d < D_; d += 256) {
    float v = (t[d]-mu)*r*s[d] + b[d];
    xr[d] = v;
    if (bo) bo[(size_t)row*D_ + d] = f2bf(v);
  }
}

// ---------------- flash attention, bf16 MFMA ------------------
#define KPITCH 136
#define VPITCH 140
#define PPITCH 72
__global__ __launch_bounds__(256) void attn_mfma_k(float* __restrict__ q,
    const float* __restrict__ kv, short* __restrict__ qbf) {
  __shared__ short Ks[64*KPITCH];
  __shared__ short Vs[64*VPITCH];
  __shared__ short Ps[4*16*PPITCH];

  const int tid  = threadIdx.x;
  const int wave = tid >> 6;
  const int lane = tid & 63;
  const int g    = lane >> 4;
  const int c    = lane & 15;
  const int hh   = blockIdx.y;
  const int b    = blockIdx.z;
  const int q0   = blockIdx.x*64 + wave*16;
  const float scale = 0.088388347648318447f;  // 128^-0.5

  bf16x8 qf[4];
  {
    const float* Qp = q + ((size_t)(b*L_ + q0 + c))*D_ + hh*HD_;
    #pragma unroll
    for (int kd = 0; kd < 4; ++kd) {
      int base = kd*32 + g*8;
      #pragma unroll
      for (int i = 0; i < 8; ++i) qf[kd][i] = f2bf(Qp[base + i]);
    }
  }

  f32x4 O[8];
  #pragma unroll
  for (int i = 0; i < 8; ++i) O[i] = (f32x4){0.f,0.f,0.f,0.f};
  float mrun[4] = {-INFINITY,-INFINITY,-INFINITY,-INFINITY};
  float lrun[4] = {0.f,0.f,0.f,0.f};

  short* Pw = Ps + wave*16*PPITCH;
  const int kr = tid >> 2;
  const int d0 = (tid & 3) * 32;

  for (int t = 0; t < L_/64; ++t) {
    __syncthreads();
    {
      const float* Krow = kv + ((size_t)(b*L_ + t*64 + kr))*2048 + hh*256;
      const float* Vrow = Krow + HD_;
      #pragma unroll
      for (int j = 0; j < 8; ++j) {
        float4 kk = *(const float4*)(Krow + d0 + j*4);
        float4 vv = *(const float4*)(Vrow + d0 + j*4);
        short4v ks4 = { f2bf(kk.x), f2bf(kk.y), f2bf(kk.z), f2bf(kk.w) };
        short4v vs4 = { f2bf(vv.x), f2bf(vv.y), f2bf(vv.z), f2bf(vv.w) };
        *(short4v*)&Ks[kr*KPITCH + d0 + j*4] = ks4;
        *(short4v*)&Vs[kr*VPITCH + d0 + j*4] = vs4;
      }
    }
    __syncthreads();

    f32x4 s[4];
    #pragma unroll
    for (int nc = 0; nc < 4; ++nc) {
      s[nc] = (f32x4){0.f,0.f,0.f,0.f};
      #pragma unroll
      for (int kd = 0; kd < 4; ++kd) {
        bf16x8 kf = *(const bf16x8*)&Ks[(nc*16 + c)*KPITCH + kd*32 + g*8];
        s[nc] = MFMA16(qf[kd], kf, s[nc]);
      }
      #pragma unroll
      for (int r = 0; r < 4; ++r) s[nc][r] *= scale;
    }

    float tm[4], rsum[4], alpha[4];
    #pragma unroll
    for (int r = 0; r < 4; ++r)
      tm[r] = fmaxf(fmaxf(s[0][r], s[1][r]), fmaxf(s[2][r], s[3][r]));
    #pragma unroll
    for (int r = 0; r < 4; ++r) {
      #pragma unroll
      for (int mask = 1; mask <= 8; mask <<= 1)
        tm[r] = fmaxf(tm[r], __shfl_xor(tm[r], mask));
      float mnew = fmaxf(mrun[r], tm[r]);
      alpha[r] = expf(mrun[r] - mnew);
      mrun[r] = mnew;
      rsum[r] = 0.f;
    }
    #pragma unroll
    for (int nc = 0; nc < 4; ++nc)
      #pragma unroll
      for (int r = 0; r < 4; ++r) {
        float p = expf(s[nc][r] - mrun[r]);
        s[nc][r] = p;
        rsum[r] += p;
      }
    #pragma unroll
    for (int r = 0; r < 4; ++r) {
      #pragma unroll
      for (int mask = 1; mask <= 8; mask <<= 1)
        rsum[r] += __shfl_xor(rsum[r], mask);
      lrun[r] = lrun[r]*alpha[r] + rsum[r];
    }
    #pragma unroll
    for (int nc = 0; nc < 8; ++nc)
      #pragma unroll
      for (int r = 0; r < 4; ++r) O[nc][r] *= alpha[r];

    #pragma unroll
    for (int nc = 0; nc < 4; ++nc)
      #pragma unroll
      for (int r = 0; r < 4; ++r)
        Pw[(g*4+r)*PPITCH + nc*16 + c] = f2bf(s[nc][r]);
    asm volatile("s_waitcnt lgkmcnt(0)" ::: "memory");
    bf16x8 pa0 = *(const bf16x8*)&Pw[c*PPITCH + g*8];
    bf16x8 pa1 = *(const bf16x8*)&Pw[c*PPITCH + 32 + g*8];

    #pragma unroll
    for (int ks = 0; ks < 2; ++ks) {
      #pragma unroll
      for (int nc = 0; nc < 8; ++nc) {
        bf16x8 vf;
        #pragma unroll
        for (int i = 0; i < 8; ++i)
          vf[i] = Vs[(ks*32 + g*8 + i)*VPITCH + nc*16 + c];
        O[nc] = MFMA16(ks ? pa1 : pa0, vf, O[nc]);
      }
    }
  }

  float* op = q + ((size_t)(b*L_ + q0))*D_ + hh*HD_;
  short* ob = qbf + ((size_t)(b*L_ + q0))*D_ + hh*HD_;
  #pragma unroll
  for (int r = 0; r < 4; ++r) {
    float inv = 1.f / lrun[r];
    #pragma unroll
    for (int nc = 0; nc < 8; ++nc) {
      float v = O[nc][r] * inv;
      op[(size_t)(g*4+r)*D_ + nc*16 + c] = v;
      ob[(size_t)(g*4+r)*D_ + nc*16 + c] = f2bf(v);
    }
  }
}

// ---------------- heads ----------------
__global__ __launch_bounds__(256) void lm_head_k(const float* __restrict__ h,
    const float* __restrict__ lm_w, float* __restrict__ out) {
  int tid = threadIdx.x;
  int n = blockIdx.x*256 + tid;
  __shared__ float last0[D_], last1[D_];
  const float* h0 = h + ((size_t)0*L_ + (L_-1))*D_;
  const float* h1 = h + ((size_t)1*L_ + (L_-1))*D_;
  for (int d = tid; d < D_; d += 256) { last0[d] = h0[d]; last1[d] = h1[d]; }
  __syncthreads();
  float a0 = 0.f, a1 = 0.f;
  for (int k = 0; k < D_; ++k) {
    float w = lm_w[(size_t)k*VOCAB_ + n];
    a0 += last0[k]*w; a1 += last1[k]*w;
  }
  out[n] = a0;
  out[(size_t)VOCAB_ + n] = a1;
}

__global__ __launch_bounds__(128) void tool_head_k(const float* __restrict__ h,
    const float* __restrict__ tw, const float* __restrict__ tb, float* __restrict__ out) {
  int b = blockIdx.x;
  int tid = threadIdx.x;
  __shared__ float last[D_];
  const float* hr = h + ((size_t)b*L_ + (L_-1))*D_;
  for (int d = tid; d < D_; d += 128) last[d] = hr[d];
  __syncthreads();
  float acc = tb[tid];
  for (int k = 0; k < D_; ++k) acc += last[k]*tw[(size_t)k*TOOLV_ + tid];
  out[(size_t)2*VOCAB_ + (size_t)b*TOOLV_ + tid] = acc;
}

extern "C" void kernel_launch(void* const* d_in, const int* in_sizes, int n_in,
                              void* d_out, int out_size, void* d_ws, size_t ws_size,
                              hipStream_t stream) {
  const float* cs        = (const float*)d_in[1];
  const float* proj_w    = (const float*)d_in[2];
  const float* emb_scale = (const float*)d_in[3];
  const float* conv_dw_w = (const float*)d_in[4];
  const float* conv_dw_b = (const float*)d_in[5];
  const float* conv_pw_w = (const float*)d_in[6];
  const float* conv_pw_b = (const float*)d_in[7];
  const float* conv_ln_s = (const float*)d_in[8];
  const float* conv_ln_b = (const float*)d_in[9];
  const float* attn_q_w  = (const float*)d_in[10];
  const float* attn_kv_w = (const float*)d_in[11];
  const float* attn_out_w= (const float*)d_in[12];
  const float* attn_ln_s = (const float*)d_in[13];
  const float* attn_ln_b = (const float*)d_in[14];
  const float* lm_w      = (const float*)d_in[15];
  const float* tool_w    = (const float*)d_in[16];
  const float* tool_b    = (const float*)d_in[17];

  const int M = B_*L_;                              // 4096
  float* h    = (float*)d_ws;                       // M*D fp32
  float* buf2 = h    + (size_t)M*D_;                // M*2D fp32
  float* buf1 = buf2 + (size_t)M*2*D_;              // M*D fp32
  short* abf  = (short*)(buf1 + (size_t)M*D_);      // M*D bf16
  short* wbf  = abf + (size_t)M*D_;                 // 2D*D bf16

  julia_proj_k<<<M, 256, 0, stream>>>(cs, proj_w, emb_scale, h);

  for (int i = 0; i < NCONV_; ++i) {
    dwconv_k<<<(M*D_)/256, 256, 0, stream>>>(h, conv_dw_w + (size_t)i*D_*5,
                                             conv_dw_b + (size_t)i*D_, abf);
    cvt_bf16_k<<<(2*D_*D_)/1024, 256, 0, stream>>>(conv_pw_w + (size_t)i*2*D_*D_, wbf);
    gemm_bf16<true><<<dim3(M/128, (2*D_)/128), 256, 0, stream>>>(
        abf, wbf, conv_pw_b + (size_t)i*2*D_, buf2, M, 2*D_, D_);
    glu_ln_k<<<M, 256, 0, stream>>>(h, buf2, conv_ln_s + (size_t)i*D_,
                                    conv_ln_b + (size_t)i*D_,
                                    (i == NCONV_-1) ? abf : (short*)nullptr);
  }

  for (int i = 0; i < NATTN_; ++i) {
    // abf holds bf16(h) from previous LN
    transp_bf16_k<<<dim3(D_/32, D_/32), 256, 0, stream>>>(
        attn_q_w + (size_t)i*D_*D_, wbf, D_, D_);
    gemm_bf16<false><<<dim3(M/128, D_/128), 256, 0, stream>>>(
        abf, wbf, nullptr, buf1, M, D_, D_);
    transp_bf16_k<<<dim3((2*D_)/32, D_/32), 256, 0, stream>>>(
        attn_kv_w + (size_t)i*D_*2*D_, wbf, D_, 2*D_);
    gemm_bf16<false><<<dim3(M/128, (2*D_)/128), 256, 0, stream>>>(
        abf, wbf, nullptr, buf2, M, 2*D_, D_);
    attn_mfma_k<<<dim3(L_/64, HEADS_, B_), 256, 0, stream>>>(buf1, buf2, abf);
    transp_bf16_k<<<dim3(D_/32, D_/32), 256, 0, stream>>>(
        attn_out_w + (size_t)i*D_*D_, wbf, D_, D_);
    gemm_bf16<false><<<dim3(M/128, D_/128), 256, 0, stream>>>(
        abf, wbf, nullptr, buf2, M, D_, D_);
    resid_ln_k<<<M, 256, 0, stream>>>(h, buf2, attn_ln_s + (size_t)i*D_,
                                      attn_ln_b + (size_t)i*D_,
                                      (i < NATTN_-1) ? abf : (short*)nullptr);
  }

  lm_head_k<<<dim3(VOCAB_/256, 1), 256, 0, stream>>>(h, lm_w, (float*)d_out);
  tool_head_k<<<B_, 128, 0, stream>>>(h, tool_w, tool_b, (float*)d_out);
}

// Round 4
// 2133.937 us; speedup vs baseline: 20.9248x; 1.2197x over previous
//
#include <hip/hip_runtime.h>
#include <hip/hip_bf16.h>
#include <math.h>

#define B_ 2
#define L_ 2048
#define D_ 1024
#define VOCAB_ 65536
#define TOOLV_ 128
#define NCONV_ 10
#define NATTN_ 6
#define HEADS_ 8
#define HD_ 128
#define EPS_ 1e-5f

typedef short bf16x8 __attribute__((ext_vector_type(8)));
typedef short short4v __attribute__((ext_vector_type(4)));
typedef float f32x4 __attribute__((ext_vector_type(4)));
#define MFMA16(a,b,c) __builtin_amdgcn_mfma_f32_16x16x32_bf16(a, b, c, 0, 0, 0)

__device__ inline short f2bf(float f) {
  __hip_bfloat16 h = __float2bfloat16(f);
  return *reinterpret_cast<short*>(&h);
}

__device__ __forceinline__ void gld16(const void* g, void* l) {
  __builtin_amdgcn_global_load_lds(
      (const __attribute__((address_space(1))) unsigned int*)g,
      (__attribute__((address_space(3))) unsigned int*)l, 16, 0, 0);
}

// ---------------- Julia feats + projection ----------------
__global__ __launch_bounds__(256) void julia_proj_k(const float* __restrict__ cs,
    const float* __restrict__ pw, const float* __restrict__ esc, float* __restrict__ h) {
  int row = blockIdx.x;                       // b*L + l
  float cr = cs[2*(size_t)row], ci = cs[2*(size_t)row+1];
  float f[16];
  float zr = 0.f, zi = 0.f;
  #pragma unroll
  for (int s = 0; s < 8; ++s) {
    float nzr = zr*zr - zi*zi + cr;
    float nzi = 2.f*zr*zi + ci;
    zr = nzr; zi = nzi;
    f[2*s] = zr; f[2*s+1] = zi;
  }
  float e = esc[0];
  for (int d = threadIdx.x; d < D_; d += 256) {
    float acc = 0.f;
    #pragma unroll
    for (int i = 0; i < 16; ++i) acc += f[i]*pw[i*D_ + d];
    h[(size_t)row*D_ + d] = acc*e;
  }
}

// ---------------- depthwise conv over L (K=5, zero pad 2), bf16 out ---------
__global__ __launch_bounds__(256) void dwconv_k(const float* __restrict__ x,
    const float* __restrict__ w, const float* __restrict__ bias, short* __restrict__ y) {
  size_t idx = (size_t)blockIdx.x*256 + threadIdx.x;   // over B*L*D
  int d = (int)(idx & (D_-1));
  size_t bl = idx >> 10;
  int l = (int)(bl & (L_-1));
  size_t bbase = (bl >> 11) * (size_t)L_;              // b*L
  float acc = bias[d];
  #pragma unroll
  for (int k = 0; k < 5; ++k) {
    int ll = l + k - 2;
    if (ll >= 0 && ll < L_)
      acc += x[(bbase + ll)*D_ + d] * w[d*5 + k];
  }
  y[idx] = f2bf(acc);
}

// ---------------- weight converts ----------------
__global__ __launch_bounds__(256) void cvt_bf16_k(const float* __restrict__ x,
    short* __restrict__ y) {
  int i = blockIdx.x*256 + threadIdx.x;
  float4 v = ((const float4*)x)[i];
  short4v s = { f2bf(v.x), f2bf(v.y), f2bf(v.z), f2bf(v.w) };
  ((short4v*)y)[i] = s;
}

// (K,N) fp32 -> (N,K) bf16 transpose
__global__ __launch_bounds__(256) void transp_bf16_k(const float* __restrict__ W,
    short* __restrict__ WT, int K, int N) {
  __shared__ short t[32][33];
  int n0 = blockIdx.x*32, k0 = blockIdx.y*32;
  int tx = threadIdx.x & 31, ty = threadIdx.x >> 5;   // ty 0..7
  #pragma unroll
  for (int i = 0; i < 4; ++i) {
    int k = ty + i*8;
    t[tx][k] = f2bf(W[(size_t)(k0+k)*N + n0 + tx]);
  }
  __syncthreads();
  #pragma unroll
  for (int i = 0; i < 4; ++i) {
    int n = ty + i*8;
    WT[(size_t)(n0+n)*K + k0 + tx] = t[n][tx];
  }
}

// ---------------- bf16 MFMA GEMM: A(M,K)bf16 x Bt(N,K)bf16 -----
// MODE 0: fp32 C (+bias).  MODE 1: bf16 C, scaled.  MODE 2: split K/Vt bf16.
template<int MODE, bool BIAS>
__global__ __launch_bounds__(256) void gemm_bf16(const short* __restrict__ A,
    const short* __restrict__ Bt, const float* __restrict__ bias,
    float* __restrict__ C, short* __restrict__ obf,
    short* __restrict__ kbf, short* __restrict__ vtbf,
    float scale, int M, int N, int K) {
  __shared__ short As[128*32];
  __shared__ short Bs[128*32];
  const int tid  = threadIdx.x;
  const int lane = tid & 63;
  const int wave = tid >> 6;
  const int wm = wave >> 1, wn = wave & 1;
  const int g = lane >> 4, c = lane & 15;
  const int m0 = blockIdx.x * 128, n0 = blockIdx.y * 128;

  f32x4 acc[4][4];
  #pragma unroll
  for (int i = 0; i < 4; ++i)
    #pragma unroll
    for (int j = 0; j < 4; ++j) acc[i][j] = (f32x4){0.f,0.f,0.f,0.f};

  const int srow = wave*16 + (lane>>2);
  const int scol = (lane&3)*8;
  const short* aSrc0 = A + (size_t)(m0 + srow)*K + scol;
  const short* aSrc1 = aSrc0 + (size_t)64*K;
  const short* bSrc0 = Bt + (size_t)(n0 + srow)*K + scol;
  const short* bSrc1 = bSrc0 + (size_t)64*K;
  short* AsW = &As[wave*512];
  short* BsW = &Bs[wave*512];

  for (int k0 = 0; k0 < K; k0 += 32) {
    __syncthreads();
    gld16(aSrc0 + k0, AsW);
    gld16(aSrc1 + k0, AsW + 2048);
    gld16(bSrc0 + k0, BsW);
    gld16(bSrc1 + k0, BsW + 2048);
    asm volatile("s_waitcnt vmcnt(0)" ::: "memory");
    __syncthreads();

    bf16x8 af[4], bfr[4];
    #pragma unroll
    for (int mi = 0; mi < 4; ++mi)
      af[mi] = *(const bf16x8*)&As[(wm*64 + mi*16 + c)*32 + g*8];
    #pragma unroll
    for (int ni = 0; ni < 4; ++ni)
      bfr[ni] = *(const bf16x8*)&Bs[(wn*64 + ni*16 + c)*32 + g*8];
    #pragma unroll
    for (int mi = 0; mi < 4; ++mi)
      #pragma unroll
      for (int ni = 0; ni < 4; ++ni)
        acc[mi][ni] = MFMA16(af[mi], bfr[ni], acc[mi][ni]);
  }

  #pragma unroll
  for (int mi = 0; mi < 4; ++mi) {
    int row = m0 + wm*64 + mi*16 + g*4;
    #pragma unroll
    for (int ni = 0; ni < 4; ++ni) {
      int col = n0 + wn*64 + ni*16 + c;
      if (MODE == 0) {
        float bv = BIAS ? bias[col] : 0.f;
        #pragma unroll
        for (int r = 0; r < 4; ++r)
          C[(size_t)(row+r)*N + col] = acc[mi][ni][r] + bv;
      } else if (MODE == 1) {
        #pragma unroll
        for (int r = 0; r < 4; ++r)
          obf[(size_t)(row+r)*N + col] = f2bf(acc[mi][ni][r]*scale);
      } else {
        int hh = col >> 8, jj = (col >> 7) & 1, d = col & 127;
        int bb = row >> 11, l = row & 2047;
        size_t bh = (size_t)bb*8 + hh;
        if (jj == 0) {
          #pragma unroll
          for (int r = 0; r < 4; ++r)
            kbf[(bh*L_ + l + r)*128 + d] = f2bf(acc[mi][ni][r]);
        } else {
          #pragma unroll
          for (int r = 0; r < 4; ++r)
            vtbf[(bh*128 + d)*L_ + l + r] = f2bf(acc[mi][ni][r]);
        }
      }
    }
  }
}

// ---------------- GLU + residual + LayerNorm (in-place on h, opt bf16 out) ---
__global__ __launch_bounds__(256) void glu_ln_k(float* __restrict__ h,
    const float* __restrict__ y2, const float* __restrict__ s, const float* __restrict__ b,
    short* __restrict__ bo) {
  int row = blockIdx.x;
  int tid = threadIdx.x;
  float* xr = h + (size_t)row*D_;
  const float* yr = y2 + (size_t)row*2*D_;
  __shared__ float t[D_];
  __shared__ float red[256];
  float ls = 0.f;
  for (int d = tid; d < D_; d += 256) {
    float a = yr[d], g = yr[D_ + d];
    float sg = 1.f/(1.f + expf(-g));
    float v = xr[d] + a*sg;
    t[d] = v; ls += v;
  }
  red[tid] = ls; __syncthreads();
  for (int st = 128; st > 0; st >>= 1) { if (tid < st) red[tid] += red[tid+st]; __syncthreads(); }
  float mu = red[0] * (1.f/D_); __syncthreads();
  float lv = 0.f;
  for (int d = tid; d < D_; d += 256) { float dd = t[d]-mu; lv += dd*dd; }
  red[tid] = lv; __syncthreads();
  for (int st = 128; st > 0; st >>= 1) { if (tid < st) red[tid] += red[tid+st]; __syncthreads(); }
  float var = red[0] * (1.f/D_);
  float r = 1.f/sqrtf(var + EPS_);
  for (int d = tid; d < D_; d += 256) {
    float v = (t[d]-mu)*r*s[d] + b[d];
    xr[d] = v;
    if (bo) bo[(size_t)row*D_ + d] = f2bf(v);
  }
}

// ---------------- residual + LayerNorm (attention epilogue, opt bf16 out) ----
__global__ __launch_bounds__(256) void resid_ln_k(float* __restrict__ h,
    const float* __restrict__ proj, const float* __restrict__ s, const float* __restrict__ b,
    short* __restrict__ bo) {
  int row = blockIdx.x;
  int tid = threadIdx.x;
  float* xr = h + (size_t)row*D_;
  const float* pr = proj + (size_t)row*D_;
  __shared__ float t[D_];
  __shared__ float red[256];
  float ls = 0.f;
  for (int d = tid; d < D_; d += 256) { float v = xr[d] + pr[d]; t[d] = v; ls += v; }
  red[tid] = ls; __syncthreads();
  for (int st = 128; st > 0; st >>= 1) { if (tid < st) red[tid] += red[tid+st]; __syncthreads(); }
  float mu = red[0] * (1.f/D_); __syncthreads();
  float lv = 0.f;
  for (int d = tid; d < D_; d += 256) { float dd = t[d]-mu; lv += dd*dd; }
  red[tid] = lv; __syncthreads();
  for (int st = 128; st > 0; st >>= 1) { if (tid < st) red[tid] += red[tid+st]; __syncthreads(); }
  float var = red[0] * (1.f/D_);
  float r = 1.f/sqrtf(var + EPS_);
  for (int d = tid; d < D_; d += 256) {
    float v = (t[d]-mu)*r*s[d] + b[d];
    xr[d] = v;
    if (bo) bo[(size_t)row*D_ + d] = f2bf(v);
  }
}

// ---------------- flash attention v2: all-bf16 inputs, swizzled LDS ----------
// qbf: (B,L,1024) pre-scaled bf16.  kbf: (B,H,L,128).  vtbf: (B,H,128,L).
// obf: (B,L,1024) bf16 out.
#define PPITCH 72
__global__ __launch_bounds__(256) void attn2_k(const short* __restrict__ qbf,
    const short* __restrict__ kbf, const short* __restrict__ vtbf,
    short* __restrict__ obf) {
  __shared__ short Ks[64*128];    // [kv 64][d 128] swizzled in 16B blocks (16/row)
  __shared__ short Vts[128*64];   // [d 128][kv 64] swizzled (8/row)
  __shared__ short Ps[4*16*PPITCH];

  const int tid  = threadIdx.x;
  const int wave = tid >> 6;
  const int lane = tid & 63;
  const int g    = lane >> 4;
  const int c    = lane & 15;
  const int hh   = blockIdx.y;
  const int b    = blockIdx.z;
  const int q0   = blockIdx.x*64 + wave*16;
  const size_t bh = (size_t)(b*HEADS_ + hh);

  // Q fragments (pre-scaled bf16, direct global)
  bf16x8 qf[4];
  {
    const short* Qp = qbf + ((size_t)(b*L_ + q0 + c))*D_ + hh*HD_;
    #pragma unroll
    for (int kd = 0; kd < 4; ++kd)
      qf[kd] = *(const bf16x8*)(Qp + kd*32 + g*8);
  }

  f32x4 O[8];
  #pragma unroll
  for (int i = 0; i < 8; ++i) O[i] = (f32x4){0.f,0.f,0.f,0.f};
  float mrun[4] = {-INFINITY,-INFINITY,-INFINITY,-INFINITY};
  float lrun[4] = {0.f,0.f,0.f,0.f};
  short* Pw = Ps + wave*16*PPITCH;

  // staging decomposition (per 16B slot): K: r=slot>>4, j=slot&15 ; Vt: r=slot>>3, j=slot&7
  const short* kBase = kbf + bh*L_*128;
  const short* vBase = vtbf + bh*128*L_;

  for (int t = 0; t < L_/64; ++t) {
    __syncthreads();
    #pragma unroll
    for (int rd = 0; rd < 4; ++rd) {
      int slot = rd*256 + tid;
      int kr = slot >> 4, kj = slot & 15;
      int vr = slot >> 3, vj = slot & 7;
      gld16(kBase + ((size_t)(t*64 + kr))*128 + ((kj ^ (kr & 15)) * 8),
            (char*)Ks + (rd*256 + wave*64)*16);
      gld16(vBase + (size_t)vr*L_ + t*64 + ((vj ^ (vr & 7)) * 8),
            (char*)Vts + (rd*256 + wave*64)*16);
    }
    asm volatile("s_waitcnt vmcnt(0)" ::: "memory");
    __syncthreads();

    // ---- S = Q K^T (Q pre-scaled) ----
    f32x4 s[4];
    #pragma unroll
    for (int nc = 0; nc < 4; ++nc) {
      s[nc] = (f32x4){0.f,0.f,0.f,0.f};
      int R = nc*16 + c;
      #pragma unroll
      for (int kd = 0; kd < 4; ++kd) {
        bf16x8 kf = *(const bf16x8*)&Ks[R*128 + (((kd*4 + g) ^ (R & 15)) * 8)];
        s[nc] = MFMA16(qf[kd], kf, s[nc]);
      }
    }

    // ---- online softmax ----
    float tm[4], rsum[4], alpha[4];
    #pragma unroll
    for (int r = 0; r < 4; ++r)
      tm[r] = fmaxf(fmaxf(s[0][r], s[1][r]), fmaxf(s[2][r], s[3][r]));
    #pragma unroll
    for (int r = 0; r < 4; ++r) {
      #pragma unroll
      for (int mask = 1; mask <= 8; mask <<= 1)
        tm[r] = fmaxf(tm[r], __shfl_xor(tm[r], mask));
      float mnew = fmaxf(mrun[r], tm[r]);
      alpha[r] = expf(mrun[r] - mnew);
      mrun[r] = mnew;
      rsum[r] = 0.f;
    }
    #pragma unroll
    for (int nc = 0; nc < 4; ++nc)
      #pragma unroll
      for (int r = 0; r < 4; ++r) {
        float p = expf(s[nc][r] - mrun[r]);
        s[nc][r] = p;
        rsum[r] += p;
      }
    #pragma unroll
    for (int r = 0; r < 4; ++r) {
      #pragma unroll
      for (int mask = 1; mask <= 8; mask <<= 1)
        rsum[r] += __shfl_xor(rsum[r], mask);
      lrun[r] = lrun[r]*alpha[r] + rsum[r];
    }
    #pragma unroll
    for (int nc = 0; nc < 8; ++nc)
      #pragma unroll
      for (int r = 0; r < 4; ++r) O[nc][r] *= alpha[r];

    // ---- P -> bf16 via per-wave LDS (A-fragment re-layout) ----
    #pragma unroll
    for (int nc = 0; nc < 4; ++nc)
      #pragma unroll
      for (int r = 0; r < 4; ++r)
        Pw[(g*4+r)*PPITCH + nc*16 + c] = f2bf(s[nc][r]);
    asm volatile("s_waitcnt lgkmcnt(0)" ::: "memory");
    bf16x8 pa0 = *(const bf16x8*)&Pw[c*PPITCH + g*8];
    bf16x8 pa1 = *(const bf16x8*)&Pw[c*PPITCH + 32 + g*8];

    // ---- O += P V  (V^T fragments, b128 swizzled reads) ----
    #pragma unroll
    for (int ks = 0; ks < 2; ++ks) {
      #pragma unroll
      for (int nc = 0; nc < 8; ++nc) {
        int R = nc*16 + c;
        bf16x8 vf = *(const bf16x8*)&Vts[R*64 + (((ks*4 + g) ^ (R & 7)) * 8)];
        O[nc] = MFMA16(ks ? pa1 : pa0, vf, O[nc]);
      }
    }
  }

  // ---- epilogue: O / l, bf16 out ----
  short* ob = obf + ((size_t)(b*L_ + q0))*D_ + hh*HD_;
  #pragma unroll
  for (int r = 0; r < 4; ++r) {
    float inv = 1.f / lrun[r];
    #pragma unroll
    for (int nc = 0; nc < 8; ++nc)
      ob[(size_t)(g*4+r)*D_ + nc*16 + c] = f2bf(O[nc][r] * inv);
  }
}

// ---------------- heads ----------------
__global__ __launch_bounds__(256) void lm_head_k(const float* __restrict__ h,
    const float* __restrict__ lm_w, float* __restrict__ out) {
  int tid = threadIdx.x;
  int n = blockIdx.x*256 + tid;
  __shared__ float last0[D_], last1[D_];
  const float* h0 = h + ((size_t)0*L_ + (L_-1))*D_;
  const float* h1 = h + ((size_t)1*L_ + (L_-1))*D_;
  for (int d = tid; d < D_; d += 256) { last0[d] = h0[d]; last1[d] = h1[d]; }
  __syncthreads();
  float a0 = 0.f, a1 = 0.f;
  for (int k = 0; k < D_; ++k) {
    float w = lm_w[(size_t)k*VOCAB_ + n];
    a0 += last0[k]*w; a1 += last1[k]*w;
  }
  out[n] = a0;
  out[(size_t)VOCAB_ + n] = a1;
}

__global__ __launch_bounds__(128) void tool_head_k(const float* __restrict__ h,
    const float* __restrict__ tw, const float* __restrict__ tb, float* __restrict__ out) {
  int b = blockIdx.x;
  int tid = threadIdx.x;
  __shared__ float last[D_];
  const float* hr = h + ((size_t)b*L_ + (L_-1))*D_;
  for (int d = tid; d < D_; d += 128) last[d] = hr[d];
  __syncthreads();
  float acc = tb[tid];
  for (int k = 0; k < D_; ++k) acc += last[k]*tw[(size_t)k*TOOLV_ + tid];
  out[(size_t)2*VOCAB_ + (size_t)b*TOOLV_ + tid] = acc;
}

extern "C" void kernel_launch(void* const* d_in, const int* in_sizes, int n_in,
                              void* d_out, int out_size, void* d_ws, size_t ws_size,
                              hipStream_t stream) {
  const float* cs        = (const float*)d_in[1];
  const float* proj_w    = (const float*)d_in[2];
  const float* emb_scale = (const float*)d_in[3];
  const float* conv_dw_w = (const float*)d_in[4];
  const float* conv_dw_b = (const float*)d_in[5];
  const float* conv_pw_w = (const float*)d_in[6];
  const float* conv_pw_b = (const float*)d_in[7];
  const float* conv_ln_s = (const float*)d_in[8];
  const float* conv_ln_b = (const float*)d_in[9];
  const float* attn_q_w  = (const float*)d_in[10];
  const float* attn_kv_w = (const float*)d_in[11];
  const float* attn_out_w= (const float*)d_in[12];
  const float* attn_ln_s = (const float*)d_in[13];
  const float* attn_ln_b = (const float*)d_in[14];
  const float* lm_w      = (const float*)d_in[15];
  const float* tool_w    = (const float*)d_in[16];
  const float* tool_b    = (const float*)d_in[17];

  const int M = B_*L_;                              // 4096
  float* h    = (float*)d_ws;                       // M*D fp32
  float* buf2 = h    + (size_t)M*D_;                // M*2D fp32 (conv y2 / attn proj + qbf)
  short* kbf  = (short*)(buf2 + (size_t)M*2*D_);    // B*H*L*128 bf16
  short* vtbf = kbf + (size_t)B_*HEADS_*L_*128;     // B*H*128*L bf16
  short* abf  = (short*)(vtbf + (size_t)B_*HEADS_*128*L_);  // M*D bf16
  short* wbf  = abf + (size_t)M*D_;                 // 2D*D bf16
  short* qbf  = (short*)(buf2 + (size_t)M*D_);      // M*D bf16 (upper half of buf2)

  const float scale = 0.088388347648318447f;        // 128^-0.5

  julia_proj_k<<<M, 256, 0, stream>>>(cs, proj_w, emb_scale, h);

  for (int i = 0; i < NCONV_; ++i) {
    dwconv_k<<<(M*D_)/256, 256, 0, stream>>>(h, conv_dw_w + (size_t)i*D_*5,
                                             conv_dw_b + (size_t)i*D_, abf);
    cvt_bf16_k<<<(2*D_*D_)/1024, 256, 0, stream>>>(conv_pw_w + (size_t)i*2*D_*D_, wbf);
    gemm_bf16<0, true><<<dim3(M/128, (2*D_)/128), 256, 0, stream>>>(
        abf, wbf, conv_pw_b + (size_t)i*2*D_, buf2, nullptr, nullptr, nullptr,
        1.f, M, 2*D_, D_);
    glu_ln_k<<<M, 256, 0, stream>>>(h, buf2, conv_ln_s + (size_t)i*D_,
                                    conv_ln_b + (size_t)i*D_,
                                    (i == NCONV_-1) ? abf : (short*)nullptr);
  }

  for (int i = 0; i < NATTN_; ++i) {
    // abf holds bf16(h) from previous LN
    transp_bf16_k<<<dim3(D_/32, D_/32), 256, 0, stream>>>(
        attn_q_w + (size_t)i*D_*D_, wbf, D_, D_);
    gemm_bf16<1, false><<<dim3(M/128, D_/128), 256, 0, stream>>>(
        abf, wbf, nullptr, nullptr, qbf, nullptr, nullptr, scale, M, D_, D_);
    transp_bf16_k<<<dim3((2*D_)/32, D_/32), 256, 0, stream>>>(
        attn_kv_w + (size_t)i*D_*2*D_, wbf, D_, 2*D_);
    gemm_bf16<2, false><<<dim3(M/128, (2*D_)/128), 256, 0, stream>>>(
        abf, wbf, nullptr, nullptr, nullptr, kbf, vtbf, 1.f, M, 2*D_, D_);
    attn2_k<<<dim3(L_/64, HEADS_, B_), 256, 0, stream>>>(qbf, kbf, vtbf, abf);
    transp_bf16_k<<<dim3(D_/32, D_/32), 256, 0, stream>>>(
        attn_out_w + (size_t)i*D_*D_, wbf, D_, D_);
    gemm_bf16<0, false><<<dim3(M/128, D_/128), 256, 0, stream>>>(
        abf, wbf, nullptr, buf2, nullptr, nullptr, nullptr, 1.f, M, D_, D_);
    resid_ln_k<<<M, 256, 0, stream>>>(h, buf2, attn_ln_s + (size_t)i*D_,
                                      attn_ln_b + (size_t)i*D_,
                                      (i < NATTN_-1) ? abf : (short*)nullptr);
  }

  lm_head_k<<<dim3(VOCAB_/256, 1), 256, 0, stream>>>(h, lm_w, (float*)d_out);
  tool_head_k<<<B_, 128, 0, stream>>>(h, tool_w, tool_b, (float*)d_out);
}

// Round 5
// 2007.780 us; speedup vs baseline: 22.2396x; 1.0628x over previous
//
#include <hip/hip_runtime.h>
#include <hip/hip_bf16.h>
#include <math.h>

#define B_ 2
#define L_ 2048
#define D_ 1024
#define VOCAB_ 65536
#define TOOLV_ 128
#define NCONV_ 10
#define NATTN_ 6
#define HEADS_ 8
#define HD_ 128
#define EPS_ 1e-5f

typedef short bf16x8 __attribute__((ext_vector_type(8)));
typedef short short4v __attribute__((ext_vector_type(4)));
typedef float f32x4 __attribute__((ext_vector_type(4)));
#define MFMA16(a,b,c) __builtin_amdgcn_mfma_f32_16x16x32_bf16(a, b, c, 0, 0, 0)

__device__ inline short f2bf(float f) {
  __hip_bfloat16 h = __float2bfloat16(f);
  return *reinterpret_cast<short*>(&h);
}

__device__ __forceinline__ void gld16(const void* g, void* l) {
  __builtin_amdgcn_global_load_lds(
      (const __attribute__((address_space(1))) unsigned int*)g,
      (__attribute__((address_space(3))) unsigned int*)l, 16, 0, 0);
}

// ---------------- Julia feats + projection ----------------
__global__ __launch_bounds__(256) void julia_proj_k(const float* __restrict__ cs,
    const float* __restrict__ pw, const float* __restrict__ esc, float* __restrict__ h) {
  int row = blockIdx.x;                       // b*L + l
  float cr = cs[2*(size_t)row], ci = cs[2*(size_t)row+1];
  float f[16];
  float zr = 0.f, zi = 0.f;
  #pragma unroll
  for (int s = 0; s < 8; ++s) {
    float nzr = zr*zr - zi*zi + cr;
    float nzi = 2.f*zr*zi + ci;
    zr = nzr; zi = nzi;
    f[2*s] = zr; f[2*s+1] = zi;
  }
  float e = esc[0];
  for (int d = threadIdx.x; d < D_; d += 256) {
    float acc = 0.f;
    #pragma unroll
    for (int i = 0; i < 16; ++i) acc += f[i]*pw[i*D_ + d];
    h[(size_t)row*D_ + d] = acc*e;
  }
}

// ---------------- depthwise conv over L (K=5, zero pad 2), bf16 out ---------
__global__ __launch_bounds__(256) void dwconv_k(const float* __restrict__ x,
    const float* __restrict__ w, const float* __restrict__ bias, short* __restrict__ y) {
  size_t idx = (size_t)blockIdx.x*256 + threadIdx.x;   // over B*L*D
  int d = (int)(idx & (D_-1));
  size_t bl = idx >> 10;
  int l = (int)(bl & (L_-1));
  size_t bbase = (bl >> 11) * (size_t)L_;              // b*L
  float acc = bias[d];
  #pragma unroll
  for (int k = 0; k < 5; ++k) {
    int ll = l + k - 2;
    if (ll >= 0 && ll < L_)
      acc += x[(bbase + ll)*D_ + d] * w[d*5 + k];
  }
  y[idx] = f2bf(acc);
}

// ---------------- bulk fp32 -> bf16 (grid-stride over float4) ----------------
__global__ __launch_bounds__(256) void cvt_bf16_k(const float* __restrict__ x,
    short* __restrict__ y, int n4) {
  int i = blockIdx.x*256 + threadIdx.x;
  if (i >= n4) return;
  float4 v = ((const float4*)x)[i];
  short4v s = { f2bf(v.x), f2bf(v.y), f2bf(v.z), f2bf(v.w) };
  ((short4v*)y)[i] = s;
}

// (K,N) fp32 -> (N,K) bf16 transpose, batched over blockIdx.z layers
__global__ __launch_bounds__(256) void transp_bf16_k(const float* __restrict__ W0,
    short* __restrict__ WT0, int K, int N, size_t srcStride, size_t dstStride) {
  const float* W = W0 + blockIdx.z*srcStride;
  short* WT = WT0 + blockIdx.z*dstStride;
  __shared__ short t[32][33];
  int n0 = blockIdx.x*32, k0 = blockIdx.y*32;
  int tx = threadIdx.x & 31, ty = threadIdx.x >> 5;   // ty 0..7
  #pragma unroll
  for (int i = 0; i < 4; ++i) {
    int k = ty + i*8;
    t[tx][k] = f2bf(W[(size_t)(k0+k)*N + n0 + tx]);
  }
  __syncthreads();
  #pragma unroll
  for (int i = 0; i < 4; ++i) {
    int n = ty + i*8;
    WT[(size_t)(n0+n)*K + k0 + tx] = t[n][tx];
  }
}

// ---------------- bf16 MFMA GEMM: A(M,K)bf16 x Bt(N,K)bf16 -----
// MODE 0: fp32 C (+bias).  MODE 3: fused QKV epilogue (col<1024 -> scaled q bf16;
//         col>=1024 -> K (b,h,L,128) / V^T (b,h,128,L) split).
template<int MODE, bool BIAS>
__global__ __launch_bounds__(256) void gemm_bf16(const short* __restrict__ A,
    const short* __restrict__ Bt, const float* __restrict__ bias,
    float* __restrict__ C, short* __restrict__ obf,
    short* __restrict__ kbf, short* __restrict__ vtbf,
    float scale, int M, int N, int K) {
  __shared__ short As[128*32];
  __shared__ short Bs[128*32];
  const int tid  = threadIdx.x;
  const int lane = tid & 63;
  const int wave = tid >> 6;
  const int wm = wave >> 1, wn = wave & 1;
  const int g = lane >> 4, c = lane & 15;
  const int m0 = blockIdx.x * 128, n0 = blockIdx.y * 128;

  f32x4 acc[4][4];
  #pragma unroll
  for (int i = 0; i < 4; ++i)
    #pragma unroll
    for (int j = 0; j < 4; ++j) acc[i][j] = (f32x4){0.f,0.f,0.f,0.f};

  const int srow = wave*16 + (lane>>2);
  const int scol = (lane&3)*8;
  const short* aSrc0 = A + (size_t)(m0 + srow)*K + scol;
  const short* aSrc1 = aSrc0 + (size_t)64*K;
  const short* bSrc0 = Bt + (size_t)(n0 + srow)*K + scol;
  const short* bSrc1 = bSrc0 + (size_t)64*K;
  short* AsW = &As[wave*512];
  short* BsW = &Bs[wave*512];

  for (int k0 = 0; k0 < K; k0 += 32) {
    __syncthreads();
    gld16(aSrc0 + k0, AsW);
    gld16(aSrc1 + k0, AsW + 2048);
    gld16(bSrc0 + k0, BsW);
    gld16(bSrc1 + k0, BsW + 2048);
    asm volatile("s_waitcnt vmcnt(0)" ::: "memory");
    __syncthreads();

    bf16x8 af[4], bfr[4];
    #pragma unroll
    for (int mi = 0; mi < 4; ++mi)
      af[mi] = *(const bf16x8*)&As[(wm*64 + mi*16 + c)*32 + g*8];
    #pragma unroll
    for (int ni = 0; ni < 4; ++ni)
      bfr[ni] = *(const bf16x8*)&Bs[(wn*64 + ni*16 + c)*32 + g*8];
    #pragma unroll
    for (int mi = 0; mi < 4; ++mi)
      #pragma unroll
      for (int ni = 0; ni < 4; ++ni)
        acc[mi][ni] = MFMA16(af[mi], bfr[ni], acc[mi][ni]);
  }

  #pragma unroll
  for (int mi = 0; mi < 4; ++mi) {
    int row = m0 + wm*64 + mi*16 + g*4;
    #pragma unroll
    for (int ni = 0; ni < 4; ++ni) {
      int col = n0 + wn*64 + ni*16 + c;
      if (MODE == 0) {
        float bv = BIAS ? bias[col] : 0.f;
        #pragma unroll
        for (int r = 0; r < 4; ++r)
          C[(size_t)(row+r)*N + col] = acc[mi][ni][r] + bv;
      } else {  // MODE 3
        if (col < 1024) {
          #pragma unroll
          for (int r = 0; r < 4; ++r)
            obf[(size_t)(row+r)*1024 + col] = f2bf(acc[mi][ni][r]*scale);
        } else {
          int col2 = col - 1024;
          int hh = col2 >> 8, jj = (col2 >> 7) & 1, d = col2 & 127;
          int bb = row >> 11, l = row & 2047;
          size_t bh = (size_t)bb*8 + hh;
          if (jj == 0) {
            #pragma unroll
            for (int r = 0; r < 4; ++r)
              kbf[(bh*L_ + l + r)*128 + d] = f2bf(acc[mi][ni][r]);
          } else {
            #pragma unroll
            for (int r = 0; r < 4; ++r)
              vtbf[(bh*128 + d)*L_ + l + r] = f2bf(acc[mi][ni][r]);
          }
        }
      }
    }
  }
}

// ---------------- GLU + residual + LayerNorm (in-place on h, opt bf16 out) ---
__global__ __launch_bounds__(256) void glu_ln_k(float* __restrict__ h,
    const float* __restrict__ y2, const float* __restrict__ s, const float* __restrict__ b,
    short* __restrict__ bo) {
  int row = blockIdx.x;
  int tid = threadIdx.x;
  float* xr = h + (size_t)row*D_;
  const float* yr = y2 + (size_t)row*2*D_;
  __shared__ float t[D_];
  __shared__ float red[256];
  float ls = 0.f;
  for (int d = tid; d < D_; d += 256) {
    float a = yr[d], g = yr[D_ + d];
    float sg = 1.f/(1.f + expf(-g));
    float v = xr[d] + a*sg;
    t[d] = v; ls += v;
  }
  red[tid] = ls; __syncthreads();
  for (int st = 128; st > 0; st >>= 1) { if (tid < st) red[tid] += red[tid+st]; __syncthreads(); }
  float mu = red[0] * (1.f/D_); __syncthreads();
  float lv = 0.f;
  for (int d = tid; d < D_; d += 256) { float dd = t[d]-mu; lv += dd*dd; }
  red[tid] = lv; __syncthreads();
  for (int st = 128; st > 0; st >>= 1) { if (tid < st) red[tid] += red[tid+st]; __syncthreads(); }
  float var = red[0] * (1.f/D_);
  float r = 1.f/sqrtf(var + EPS_);
  for (int d = tid; d < D_; d += 256) {
    float v = (t[d]-mu)*r*s[d] + b[d];
    xr[d] = v;
    if (bo) bo[(size_t)row*D_ + d] = f2bf(v);
  }
}

// ---------------- residual + LayerNorm (attention epilogue, opt bf16 out) ----
__global__ __launch_bounds__(256) void resid_ln_k(float* __restrict__ h,
    const float* __restrict__ proj, const float* __restrict__ s, const float* __restrict__ b,
    short* __restrict__ bo) {
  int row = blockIdx.x;
  int tid = threadIdx.x;
  float* xr = h + (size_t)row*D_;
  const float* pr = proj + (size_t)row*D_;
  __shared__ float t[D_];
  __shared__ float red[256];
  float ls = 0.f;
  for (int d = tid; d < D_; d += 256) { float v = xr[d] + pr[d]; t[d] = v; ls += v; }
  red[tid] = ls; __syncthreads();
  for (int st = 128; st > 0; st >>= 1) { if (tid < st) red[tid] += red[tid+st]; __syncthreads(); }
  float mu = red[0] * (1.f/D_); __syncthreads();
  float lv = 0.f;
  for (int d = tid; d < D_; d += 256) { float dd = t[d]-mu; lv += dd*dd; }
  red[tid] = lv; __syncthreads();
  for (int st = 128; st > 0; st >>= 1) { if (tid < st) red[tid] += red[tid+st]; __syncthreads(); }
  float var = red[0] * (1.f/D_);
  float r = 1.f/sqrtf(var + EPS_);
  for (int d = tid; d < D_; d += 256) {
    float v = (t[d]-mu)*r*s[d] + b[d];
    xr[d] = v;
    if (bo) bo[(size_t)row*D_ + d] = f2bf(v);
  }
}

// ---------------- flash attention: all-bf16 inputs, swizzled LDS ----------
// qbf: (B,L,1024) pre-scaled bf16.  kbf: (B,H,L,128).  vtbf: (B,H,128,L).
// obf: (B,L,1024) bf16 out.
#define PPITCH 72
__global__ __launch_bounds__(256) void attn2_k(const short* __restrict__ qbf,
    const short* __restrict__ kbf, const short* __restrict__ vtbf,
    short* __restrict__ obf) {
  __shared__ short Ks[64*128];    // [kv 64][d 128] swizzled in 16B blocks (16/row)
  __shared__ short Vts[128*64];   // [d 128][kv 64] swizzled (8/row)
  __shared__ short Ps[4*16*PPITCH];

  const int tid  = threadIdx.x;
  const int wave = tid >> 6;
  const int lane = tid & 63;
  const int g    = lane >> 4;
  const int c    = lane & 15;
  const int hh   = blockIdx.y;
  const int b    = blockIdx.z;
  const int q0   = blockIdx.x*64 + wave*16;
  const size_t bh = (size_t)(b*HEADS_ + hh);

  bf16x8 qf[4];
  {
    const short* Qp = qbf + ((size_t)(b*L_ + q0 + c))*D_ + hh*HD_;
    #pragma unroll
    for (int kd = 0; kd < 4; ++kd)
      qf[kd] = *(const bf16x8*)(Qp + kd*32 + g*8);
  }

  f32x4 O[8];
  #pragma unroll
  for (int i = 0; i < 8; ++i) O[i] = (f32x4){0.f,0.f,0.f,0.f};
  float mrun[4] = {-INFINITY,-INFINITY,-INFINITY,-INFINITY};
  float lrun[4] = {0.f,0.f,0.f,0.f};
  short* Pw = Ps + wave*16*PPITCH;

  const short* kBase = kbf + bh*L_*128;
  const short* vBase = vtbf + bh*128*L_;

  for (int t = 0; t < L_/64; ++t) {
    __syncthreads();
    #pragma unroll
    for (int rd = 0; rd < 4; ++rd) {
      int slot = rd*256 + tid;
      int kr = slot >> 4, kj = slot & 15;
      int vr = slot >> 3, vj = slot & 7;
      gld16(kBase + ((size_t)(t*64 + kr))*128 + ((kj ^ (kr & 15)) * 8),
            (char*)Ks + (rd*256 + wave*64)*16);
      gld16(vBase + (size_t)vr*L_ + t*64 + ((vj ^ (vr & 7)) * 8),
            (char*)Vts + (rd*256 + wave*64)*16);
    }
    asm volatile("s_waitcnt vmcnt(0)" ::: "memory");
    __syncthreads();

    f32x4 s[4];
    #pragma unroll
    for (int nc = 0; nc < 4; ++nc) {
      s[nc] = (f32x4){0.f,0.f,0.f,0.f};
      int R = nc*16 + c;
      #pragma unroll
      for (int kd = 0; kd < 4; ++kd) {
        bf16x8 kf = *(const bf16x8*)&Ks[R*128 + (((kd*4 + g) ^ (R & 15)) * 8)];
        s[nc] = MFMA16(qf[kd], kf, s[nc]);
      }
    }

    float tm[4], rsum[4], alpha[4];
    #pragma unroll
    for (int r = 0; r < 4; ++r)
      tm[r] = fmaxf(fmaxf(s[0][r], s[1][r]), fmaxf(s[2][r], s[3][r]));
    #pragma unroll
    for (int r = 0; r < 4; ++r) {
      #pragma unroll
      for (int mask = 1; mask <= 8; mask <<= 1)
        tm[r] = fmaxf(tm[r], __shfl_xor(tm[r], mask));
      float mnew = fmaxf(mrun[r], tm[r]);
      alpha[r] = expf(mrun[r] - mnew);
      mrun[r] = mnew;
      rsum[r] = 0.f;
    }
    #pragma unroll
    for (int nc = 0; nc < 4; ++nc)
      #pragma unroll
      for (int r = 0; r < 4; ++r) {
        float p = expf(s[nc][r] - mrun[r]);
        s[nc][r] = p;
        rsum[r] += p;
      }
    #pragma unroll
    for (int r = 0; r < 4; ++r) {
      #pragma unroll
      for (int mask = 1; mask <= 8; mask <<= 1)
        rsum[r] += __shfl_xor(rsum[r], mask);
      lrun[r] = lrun[r]*alpha[r] + rsum[r];
    }
    #pragma unroll
    for (int nc = 0; nc < 8; ++nc)
      #pragma unroll
      for (int r = 0; r < 4; ++r) O[nc][r] *= alpha[r];

    #pragma unroll
    for (int nc = 0; nc < 4; ++nc)
      #pragma unroll
      for (int r = 0; r < 4; ++r)
        Pw[(g*4+r)*PPITCH + nc*16 + c] = f2bf(s[nc][r]);
    asm volatile("s_waitcnt lgkmcnt(0)" ::: "memory");
    bf16x8 pa0 = *(const bf16x8*)&Pw[c*PPITCH + g*8];
    bf16x8 pa1 = *(const bf16x8*)&Pw[c*PPITCH + 32 + g*8];

    #pragma unroll
    for (int ks = 0; ks < 2; ++ks) {
      #pragma unroll
      for (int nc = 0; nc < 8; ++nc) {
        int R = nc*16 + c;
        bf16x8 vf = *(const bf16x8*)&Vts[R*64 + (((ks*4 + g) ^ (R & 7)) * 8)];
        O[nc] = MFMA16(ks ? pa1 : pa0, vf, O[nc]);
      }
    }
  }

  short* ob = obf + ((size_t)(b*L_ + q0))*D_ + hh*HD_;
  #pragma unroll
  for (int r = 0; r < 4; ++r) {
    float inv = 1.f / lrun[r];
    #pragma unroll
    for (int nc = 0; nc < 8; ++nc)
      ob[(size_t)(g*4+r)*D_ + nc*16 + c] = f2bf(O[nc][r] * inv);
  }
}

// ---------------- heads ----------------
__global__ __launch_bounds__(256) void lm_head_k(const float* __restrict__ h,
    const float* __restrict__ lm_w, float* __restrict__ out) {
  int tid = threadIdx.x;
  int n = blockIdx.x*256 + tid;
  __shared__ float last0[D_], last1[D_];
  const float* h0 = h + ((size_t)0*L_ + (L_-1))*D_;
  const float* h1 = h + ((size_t)1*L_ + (L_-1))*D_;
  for (int d = tid; d < D_; d += 256) { last0[d] = h0[d]; last1[d] = h1[d]; }
  __syncthreads();
  float a0 = 0.f, a1 = 0.f;
  for (int k = 0; k < D_; ++k) {
    float w = lm_w[(size_t)k*VOCAB_ + n];
    a0 += last0[k]*w; a1 += last1[k]*w;
  }
  out[n] = a0;
  out[(size_t)VOCAB_ + n] = a1;
}

__global__ __launch_bounds__(128) void tool_head_k(const float* __restrict__ h,
    const float* __restrict__ tw, const float* __restrict__ tb, float* __restrict__ out) {
  int b = blockIdx.x;
  int tid = threadIdx.x;
  __shared__ float last[D_];
  const float* hr = h + ((size_t)b*L_ + (L_-1))*D_;
  for (int d = tid; d < D_; d += 128) last[d] = hr[d];
  __syncthreads();
  float acc = tb[tid];
  for (int k = 0; k < D_; ++k) acc += last[k]*tw[(size_t)k*TOOLV_ + tid];
  out[(size_t)2*VOCAB_ + (size_t)b*TOOLV_ + tid] = acc;
}

extern "C" void kernel_launch(void* const* d_in, const int* in_sizes, int n_in,
                              void* d_out, int out_size, void* d_ws, size_t ws_size,
                              hipStream_t stream) {
  const float* cs        = (const float*)d_in[1];
  const float* proj_w    = (const float*)d_in[2];
  const float* emb_scale = (const float*)d_in[3];
  const float* conv_dw_w = (const float*)d_in[4];
  const float* conv_dw_b = (const float*)d_in[5];
  const float* conv_pw_w = (const float*)d_in[6];
  const float* conv_pw_b = (const float*)d_in[7];
  const float* conv_ln_s = (const float*)d_in[8];
  const float* conv_ln_b = (const float*)d_in[9];
  const float* attn_q_w  = (const float*)d_in[10];
  const float* attn_kv_w = (const float*)d_in[11];
  const float* attn_out_w= (const float*)d_in[12];
  const float* attn_ln_s = (const float*)d_in[13];
  const float* attn_ln_b = (const float*)d_in[14];
  const float* lm_w      = (const float*)d_in[15];
  const float* tool_w    = (const float*)d_in[16];
  const float* tool_b    = (const float*)d_in[17];

  const int M = B_*L_;                              // 4096
  float* h    = (float*)d_ws;                       // M*D fp32
  float* buf2 = h    + (size_t)M*D_;                // M*2D fp32
  short* kbf  = (short*)(buf2 + (size_t)M*2*D_);    // B*H*L*128 bf16
  short* vtbf = kbf + (size_t)B_*HEADS_*L_*128;     // B*H*128*L bf16
  short* abf  = (short*)(vtbf + (size_t)B_*HEADS_*128*L_);  // M*D bf16
  short* wconv= abf + (size_t)M*D_;                 // 10 * 2D*D bf16
  short* wqkv = wconv + (size_t)NCONV_*2*D_*D_;     // 6 * 3D*D bf16
  short* wout = wqkv + (size_t)NATTN_*3*D_*D_;      // 6 * D*D bf16
  short* qbf  = (short*)(buf2 + (size_t)M*D_);      // M*D bf16 (upper half of buf2)

  const float scale = 0.088388347648318447f;        // 128^-0.5

  // ---- batched weight prep (4 launches) ----
  {
    int n4 = NCONV_*2*D_*D_/4;
    cvt_bf16_k<<<(n4 + 255)/256, 256, 0, stream>>>(conv_pw_w, wconv, n4);
    transp_bf16_k<<<dim3(D_/32, D_/32, NATTN_), 256, 0, stream>>>(
        attn_q_w, wqkv, D_, D_, (size_t)D_*D_, (size_t)3*D_*D_);
    transp_bf16_k<<<dim3((2*D_)/32, D_/32, NATTN_), 256, 0, stream>>>(
        attn_kv_w, wqkv + (size_t)D_*D_, D_, 2*D_, (size_t)D_*2*D_, (size_t)3*D_*D_);
    transp_bf16_k<<<dim3(D_/32, D_/32, NATTN_), 256, 0, stream>>>(
        attn_out_w, wout, D_, D_, (size_t)D_*D_, (size_t)D_*D_);
  }

  julia_proj_k<<<M, 256, 0, stream>>>(cs, proj_w, emb_scale, h);

  for (int i = 0; i < NCONV_; ++i) {
    dwconv_k<<<(M*D_)/256, 256, 0, stream>>>(h, conv_dw_w + (size_t)i*D_*5,
                                             conv_dw_b + (size_t)i*D_, abf);
    gemm_bf16<0, true><<<dim3(M/128, (2*D_)/128), 256, 0, stream>>>(
        abf, wconv + (size_t)i*2*D_*D_, conv_pw_b + (size_t)i*2*D_,
        buf2, nullptr, nullptr, nullptr, 1.f, M, 2*D_, D_);
    glu_ln_k<<<M, 256, 0, stream>>>(h, buf2, conv_ln_s + (size_t)i*D_,
                                    conv_ln_b + (size_t)i*D_,
                                    (i == NCONV_-1) ? abf : (short*)nullptr);
  }

  for (int i = 0; i < NATTN_; ++i) {
    // abf holds bf16(h) from previous LN
    gemm_bf16<3, false><<<dim3(M/128, (3*D_)/128), 256, 0, stream>>>(
        abf, wqkv + (size_t)i*3*D_*D_, nullptr, nullptr, qbf, kbf, vtbf,
        scale, M, 3*D_, D_);
    attn2_k<<<dim3(L_/64, HEADS_, B_), 256, 0, stream>>>(qbf, kbf, vtbf, abf);
    gemm_bf16<0, false><<<dim3(M/128, D_/128), 256, 0, stream>>>(
        abf, wout + (size_t)i*D_*D_, nullptr, buf2, nullptr, nullptr, nullptr,
        1.f, M, D_, D_);
    resid_ln_k<<<M, 256, 0, stream>>>(h, buf2, attn_ln_s + (size_t)i*D_,
                                      attn_ln_b + (size_t)i*D_,
                                      (i < NATTN_-1) ? abf : (short*)nullptr);
  }

  lm_head_k<<<dim3(VOCAB_/256, 1), 256, 0, stream>>>(h, lm_w, (float*)d_out);
  tool_head_k<<<B_, 128, 0, stream>>>(h, tool_w, tool_b, (float*)d_out);
}

// Round 6
// 1833.821 us; speedup vs baseline: 24.3492x; 1.0949x over previous
//
#include <hip/hip_runtime.h>
#include <hip/hip_bf16.h>
#include <math.h>

#define B_ 2
#define L_ 2048
#define D_ 1024
#define VOCAB_ 65536
#define TOOLV_ 128
#define NCONV_ 10
#define NATTN_ 6
#define HEADS_ 8
#define HD_ 128
#define EPS_ 1e-5f

typedef short bf16x8 __attribute__((ext_vector_type(8)));
typedef short short4v __attribute__((ext_vector_type(4)));
typedef float f32x4 __attribute__((ext_vector_type(4)));
#define MFMA16(a,b,c) __builtin_amdgcn_mfma_f32_16x16x32_bf16(a, b, c, 0, 0, 0)

__device__ inline short f2bf(float f) {
  __hip_bfloat16 h = __float2bfloat16(f);
  return *reinterpret_cast<short*>(&h);
}

__device__ __forceinline__ void gld16(const void* g, void* l) {
  __builtin_amdgcn_global_load_lds(
      (const __attribute__((address_space(1))) unsigned int*)g,
      (__attribute__((address_space(3))) unsigned int*)l, 16, 0, 0);
}

// ---------------- Julia feats + projection (float4) ----------------
__global__ __launch_bounds__(256) void julia_proj_k(const float* __restrict__ cs,
    const float* __restrict__ pw, const float* __restrict__ esc, float* __restrict__ h) {
  int row = blockIdx.x;                       // b*L + l
  float cr = cs[2*(size_t)row], ci = cs[2*(size_t)row+1];
  float f[16];
  float zr = 0.f, zi = 0.f;
  #pragma unroll
  for (int s = 0; s < 8; ++s) {
    float nzr = zr*zr - zi*zi + cr;
    float nzi = 2.f*zr*zi + ci;
    zr = nzr; zi = nzi;
    f[2*s] = zr; f[2*s+1] = zi;
  }
  float e = esc[0];
  int d = threadIdx.x * 4;
  float4 acc = {0.f, 0.f, 0.f, 0.f};
  #pragma unroll
  for (int i = 0; i < 16; ++i) {
    float4 pv = *(const float4*)(pw + i*D_ + d);
    acc.x += f[i]*pv.x; acc.y += f[i]*pv.y; acc.z += f[i]*pv.z; acc.w += f[i]*pv.w;
  }
  acc.x *= e; acc.y *= e; acc.z *= e; acc.w *= e;
  *(float4*)(h + (size_t)row*D_ + d) = acc;
}

// ---------------- depthwise conv over L (K=5, pad 2), float4, bf16 out ------
__global__ __launch_bounds__(256) void dwconv_k(const float* __restrict__ x,
    const float* __restrict__ w, const float* __restrict__ bias, short* __restrict__ y) {
  int idx = blockIdx.x*256 + threadIdx.x;              // over M * D/4
  int d = (idx & (D_/4 - 1)) * 4;
  int bl = idx >> 8;
  int l = bl & (L_-1);
  size_t bbase = (size_t)(bl >> 11) * L_;              // b*L
  float4 acc = *(const float4*)(bias + d);
  float wr[4][5];
  #pragma unroll
  for (int j = 0; j < 4; ++j)
    #pragma unroll
    for (int k = 0; k < 5; ++k) wr[j][k] = w[(d+j)*5 + k];
  #pragma unroll
  for (int k = 0; k < 5; ++k) {
    int ll = l + k - 2;
    if (ll >= 0 && ll < L_) {
      float4 xv = *(const float4*)(x + (bbase + ll)*D_ + d);
      acc.x += xv.x*wr[0][k]; acc.y += xv.y*wr[1][k];
      acc.z += xv.z*wr[2][k]; acc.w += xv.w*wr[3][k];
    }
  }
  short4v o = { f2bf(acc.x), f2bf(acc.y), f2bf(acc.z), f2bf(acc.w) };
  ((short4v*)y)[idx] = o;
}

// ---------------- bulk fp32 -> bf16 ----------------
__global__ __launch_bounds__(256) void cvt_bf16_k(const float* __restrict__ x,
    short* __restrict__ y, int n4) {
  int i = blockIdx.x*256 + threadIdx.x;
  if (i >= n4) return;
  float4 v = ((const float4*)x)[i];
  short4v s = { f2bf(v.x), f2bf(v.y), f2bf(v.z), f2bf(v.w) };
  ((short4v*)y)[i] = s;
}

// (K,N) fp32 -> (N,K) bf16 transpose, batched over blockIdx.z layers
__global__ __launch_bounds__(256) void transp_bf16_k(const float* __restrict__ W0,
    short* __restrict__ WT0, int K, int N, size_t srcStride, size_t dstStride) {
  const float* W = W0 + blockIdx.z*srcStride;
  short* WT = WT0 + blockIdx.z*dstStride;
  __shared__ short t[32][33];
  int n0 = blockIdx.x*32, k0 = blockIdx.y*32;
  int tx = threadIdx.x & 31, ty = threadIdx.x >> 5;   // ty 0..7
  #pragma unroll
  for (int i = 0; i < 4; ++i) {
    int k = ty + i*8;
    t[tx][k] = f2bf(W[(size_t)(k0+k)*N + n0 + tx]);
  }
  __syncthreads();
  #pragma unroll
  for (int i = 0; i < 4; ++i) {
    int n = ty + i*8;
    WT[(size_t)(n0+n)*K + k0 + tx] = t[n][tx];
  }
}

// ---------------- bf16 MFMA GEMM: A(M,K)bf16 x Bt(N,K)bf16 -----
// 128x128 tile, 2 K-subtiles (BK=64) per barrier-pair, 32 MFMA per sync.
// MODE 0: fp32 C (+bias).  MODE 3: fused QKV epilogue.
template<int MODE, bool BIAS>
__global__ __launch_bounds__(256) void gemm_bf16(const short* __restrict__ A,
    const short* __restrict__ Bt, const float* __restrict__ bias,
    float* __restrict__ C, short* __restrict__ obf,
    short* __restrict__ kbf, short* __restrict__ vtbf,
    float scale, int M, int N, int K) {
  __shared__ short As[2*128*32];
  __shared__ short Bs[2*128*32];
  const int tid  = threadIdx.x;
  const int lane = tid & 63;
  const int wave = tid >> 6;
  const int wm = wave >> 1, wn = wave & 1;
  const int g = lane >> 4, c = lane & 15;
  const int m0 = blockIdx.x * 128, n0 = blockIdx.y * 128;

  f32x4 acc[4][4];
  #pragma unroll
  for (int i = 0; i < 4; ++i)
    #pragma unroll
    for (int j = 0; j < 4; ++j) acc[i][j] = (f32x4){0.f,0.f,0.f,0.f};

  const int srow = wave*16 + (lane>>2);
  const int scol = (lane&3)*8;
  const short* aSrc0 = A + (size_t)(m0 + srow)*K + scol;
  const short* aSrc1 = aSrc0 + (size_t)64*K;
  const short* bSrc0 = Bt + (size_t)(n0 + srow)*K + scol;
  const short* bSrc1 = bSrc0 + (size_t)64*K;
  short* AsW = &As[wave*512];
  short* BsW = &Bs[wave*512];

  for (int k0 = 0; k0 < K; k0 += 64) {
    __syncthreads();
    gld16(aSrc0 + k0,      AsW);
    gld16(aSrc1 + k0,      AsW + 2048);
    gld16(aSrc0 + k0 + 32, AsW + 4096);
    gld16(aSrc1 + k0 + 32, AsW + 6144);
    gld16(bSrc0 + k0,      BsW);
    gld16(bSrc1 + k0,      BsW + 2048);
    gld16(bSrc0 + k0 + 32, BsW + 4096);
    gld16(bSrc1 + k0 + 32, BsW + 6144);
    asm volatile("s_waitcnt vmcnt(0)" ::: "memory");
    __syncthreads();

    #pragma unroll
    for (int s = 0; s < 2; ++s) {
      bf16x8 af[4], bfr[4];
      #pragma unroll
      for (int mi = 0; mi < 4; ++mi)
        af[mi] = *(const bf16x8*)&As[s*4096 + (wm*64 + mi*16 + c)*32 + g*8];
      #pragma unroll
      for (int ni = 0; ni < 4; ++ni)
        bfr[ni] = *(const bf16x8*)&Bs[s*4096 + (wn*64 + ni*16 + c)*32 + g*8];
      #pragma unroll
      for (int mi = 0; mi < 4; ++mi)
        #pragma unroll
        for (int ni = 0; ni < 4; ++ni)
          acc[mi][ni] = MFMA16(af[mi], bfr[ni], acc[mi][ni]);
    }
  }

  #pragma unroll
  for (int mi = 0; mi < 4; ++mi) {
    int row = m0 + wm*64 + mi*16 + g*4;
    #pragma unroll
    for (int ni = 0; ni < 4; ++ni) {
      int col = n0 + wn*64 + ni*16 + c;
      if (MODE == 0) {
        float bv = BIAS ? bias[col] : 0.f;
        #pragma unroll
        for (int r = 0; r < 4; ++r)
          C[(size_t)(row+r)*N + col] = acc[mi][ni][r] + bv;
      } else {  // MODE 3
        if (col < 1024) {
          #pragma unroll
          for (int r = 0; r < 4; ++r)
            obf[(size_t)(row+r)*1024 + col] = f2bf(acc[mi][ni][r]*scale);
        } else {
          int col2 = col - 1024;
          int hh = col2 >> 8, jj = (col2 >> 7) & 1, d = col2 & 127;
          int bb = row >> 11, l = row & 2047;
          size_t bh = (size_t)bb*8 + hh;
          if (jj == 0) {
            #pragma unroll
            for (int r = 0; r < 4; ++r)
              kbf[(bh*L_ + l + r)*128 + d] = f2bf(acc[mi][ni][r]);
          } else {
            #pragma unroll
            for (int r = 0; r < 4; ++r)
              vtbf[(bh*128 + d)*L_ + l + r] = f2bf(acc[mi][ni][r]);
          }
        }
      }
    }
  }
}

// ---------------- GLU + residual + LayerNorm (float4, regs, opt bf16 out) ----
__global__ __launch_bounds__(256) void glu_ln_k(float* __restrict__ h,
    const float* __restrict__ y2, const float* __restrict__ s, const float* __restrict__ b,
    short* __restrict__ bo) {
  int row = blockIdx.x;
  int tid = threadIdx.x;
  int d = tid*4;
  float* xr = h + (size_t)row*D_;
  const float* yr = y2 + (size_t)row*2*D_;
  __shared__ float red[256];
  float4 xv = *(const float4*)(xr + d);
  float4 av = *(const float4*)(yr + d);
  float4 gv = *(const float4*)(yr + D_ + d);
  float v[4];
  v[0] = xv.x + av.x/(1.f + expf(-gv.x));
  v[1] = xv.y + av.y/(1.f + expf(-gv.y));
  v[2] = xv.z + av.z/(1.f + expf(-gv.z));
  v[3] = xv.w + av.w/(1.f + expf(-gv.w));
  red[tid] = v[0]+v[1]+v[2]+v[3]; __syncthreads();
  for (int st = 128; st > 0; st >>= 1) { if (tid < st) red[tid] += red[tid+st]; __syncthreads(); }
  float mu = red[0] * (1.f/D_); __syncthreads();
  float lv = 0.f;
  #pragma unroll
  for (int j = 0; j < 4; ++j) { float dd = v[j]-mu; lv += dd*dd; }
  red[tid] = lv; __syncthreads();
  for (int st = 128; st > 0; st >>= 1) { if (tid < st) red[tid] += red[tid+st]; __syncthreads(); }
  float var = red[0] * (1.f/D_);
  float r = 1.f/sqrtf(var + EPS_);
  float4 sv = *(const float4*)(s + d);
  float4 bv = *(const float4*)(b + d);
  float4 o;
  o.x = (v[0]-mu)*r*sv.x + bv.x;
  o.y = (v[1]-mu)*r*sv.y + bv.y;
  o.z = (v[2]-mu)*r*sv.z + bv.z;
  o.w = (v[3]-mu)*r*sv.w + bv.w;
  *(float4*)(xr + d) = o;
  if (bo) {
    short4v ob = { f2bf(o.x), f2bf(o.y), f2bf(o.z), f2bf(o.w) };
    *(short4v*)(bo + (size_t)row*D_ + d) = ob;
  }
}

// ---------------- residual + LayerNorm (float4, regs, opt bf16 out) ----------
__global__ __launch_bounds__(256) void resid_ln_k(float* __restrict__ h,
    const float* __restrict__ proj, const float* __restrict__ s, const float* __restrict__ b,
    short* __restrict__ bo) {
  int row = blockIdx.x;
  int tid = threadIdx.x;
  int d = tid*4;
  float* xr = h + (size_t)row*D_;
  const float* pr = proj + (size_t)row*D_;
  __shared__ float red[256];
  float4 xv = *(const float4*)(xr + d);
  float4 pv = *(const float4*)(pr + d);
  float v[4] = { xv.x+pv.x, xv.y+pv.y, xv.z+pv.z, xv.w+pv.w };
  red[tid] = v[0]+v[1]+v[2]+v[3]; __syncthreads();
  for (int st = 128; st > 0; st >>= 1) { if (tid < st) red[tid] += red[tid+st]; __syncthreads(); }
  float mu = red[0] * (1.f/D_); __syncthreads();
  float lv = 0.f;
  #pragma unroll
  for (int j = 0; j < 4; ++j) { float dd = v[j]-mu; lv += dd*dd; }
  red[tid] = lv; __syncthreads();
  for (int st = 128; st > 0; st >>= 1) { if (tid < st) red[tid] += red[tid+st]; __syncthreads(); }
  float var = red[0] * (1.f/D_);
  float r = 1.f/sqrtf(var + EPS_);
  float4 sv = *(const float4*)(s + d);
  float4 bv = *(const float4*)(b + d);
  float4 o;
  o.x = (v[0]-mu)*r*sv.x + bv.x;
  o.y = (v[1]-mu)*r*sv.y + bv.y;
  o.z = (v[2]-mu)*r*sv.z + bv.z;
  o.w = (v[3]-mu)*r*sv.w + bv.w;
  *(float4*)(xr + d) = o;
  if (bo) {
    short4v ob = { f2bf(o.x), f2bf(o.y), f2bf(o.z), f2bf(o.w) };
    *(short4v*)(bo + (size_t)row*D_ + d) = ob;
  }
}

// ---------------- flash attention: all-bf16 inputs, swizzled LDS ----------
#define PPITCH 72
__global__ __launch_bounds__(256) void attn2_k(const short* __restrict__ qbf,
    const short* __restrict__ kbf, const short* __restrict__ vtbf,
    short* __restrict__ obf) {
  __shared__ short Ks[64*128];    // [kv 64][d 128] swizzled in 16B blocks (16/row)
  __shared__ short Vts[128*64];   // [d 128][kv 64] swizzled (8/row)
  __shared__ short Ps[4*16*PPITCH];

  const int tid  = threadIdx.x;
  const int wave = tid >> 6;
  const int lane = tid & 63;
  const int g    = lane >> 4;
  const int c    = lane & 15;
  const int hh   = blockIdx.y;
  const int b    = blockIdx.z;
  const int q0   = blockIdx.x*64 + wave*16;
  const size_t bh = (size_t)(b*HEADS_ + hh);

  bf16x8 qf[4];
  {
    const short* Qp = qbf + ((size_t)(b*L_ + q0 + c))*D_ + hh*HD_;
    #pragma unroll
    for (int kd = 0; kd < 4; ++kd)
      qf[kd] = *(const bf16x8*)(Qp + kd*32 + g*8);
  }

  f32x4 O[8];
  #pragma unroll
  for (int i = 0; i < 8; ++i) O[i] = (f32x4){0.f,0.f,0.f,0.f};
  float mrun[4] = {-INFINITY,-INFINITY,-INFINITY,-INFINITY};
  float lrun[4] = {0.f,0.f,0.f,0.f};
  short* Pw = Ps + wave*16*PPITCH;

  const short* kBase = kbf + bh*L_*128;
  const short* vBase = vtbf + bh*128*L_;

  for (int t = 0; t < L_/64; ++t) {
    __syncthreads();
    #pragma unroll
    for (int rd = 0; rd < 4; ++rd) {
      int slot = rd*256 + tid;
      int kr = slot >> 4, kj = slot & 15;
      int vr = slot >> 3, vj = slot & 7;
      gld16(kBase + ((size_t)(t*64 + kr))*128 + ((kj ^ (kr & 15)) * 8),
            (char*)Ks + (rd*256 + wave*64)*16);
      gld16(vBase + (size_t)vr*L_ + t*64 + ((vj ^ (vr & 7)) * 8),
            (char*)Vts + (rd*256 + wave*64)*16);
    }
    asm volatile("s_waitcnt vmcnt(0)" ::: "memory");
    __syncthreads();

    f32x4 s[4];
    #pragma unroll
    for (int nc = 0; nc < 4; ++nc) {
      s[nc] = (f32x4){0.f,0.f,0.f,0.f};
      int R = nc*16 + c;
      #pragma unroll
      for (int kd = 0; kd < 4; ++kd) {
        bf16x8 kf = *(const bf16x8*)&Ks[R*128 + (((kd*4 + g) ^ (R & 15)) * 8)];
        s[nc] = MFMA16(qf[kd], kf, s[nc]);
      }
    }

    float tm[4], rsum[4], alpha[4];
    #pragma unroll
    for (int r = 0; r < 4; ++r)
      tm[r] = fmaxf(fmaxf(s[0][r], s[1][r]), fmaxf(s[2][r], s[3][r]));
    #pragma unroll
    for (int r = 0; r < 4; ++r) {
      #pragma unroll
      for (int mask = 1; mask <= 8; mask <<= 1)
        tm[r] = fmaxf(tm[r], __shfl_xor(tm[r], mask));
      float mnew = fmaxf(mrun[r], tm[r]);
      alpha[r] = expf(mrun[r] - mnew);
      mrun[r] = mnew;
      rsum[r] = 0.f;
    }
    #pragma unroll
    for (int nc = 0; nc < 4; ++nc)
      #pragma unroll
      for (int r = 0; r < 4; ++r) {
        float p = expf(s[nc][r] - mrun[r]);
        s[nc][r] = p;
        rsum[r] += p;
      }
    #pragma unroll
    for (int r = 0; r < 4; ++r) {
      #pragma unroll
      for (int mask = 1; mask <= 8; mask <<= 1)
        rsum[r] += __shfl_xor(rsum[r], mask);
      lrun[r] = lrun[r]*alpha[r] + rsum[r];
    }
    #pragma unroll
    for (int nc = 0; nc < 8; ++nc)
      #pragma unroll
      for (int r = 0; r < 4; ++r) O[nc][r] *= alpha[r];

    #pragma unroll
    for (int nc = 0; nc < 4; ++nc)
      #pragma unroll
      for (int r = 0; r < 4; ++r)
        Pw[(g*4+r)*PPITCH + nc*16 + c] = f2bf(s[nc][r]);
    asm volatile("s_waitcnt lgkmcnt(0)" ::: "memory");
    bf16x8 pa0 = *(const bf16x8*)&Pw[c*PPITCH + g*8];
    bf16x8 pa1 = *(const bf16x8*)&Pw[c*PPITCH + 32 + g*8];

    #pragma unroll
    for (int ks = 0; ks < 2; ++ks) {
      #pragma unroll
      for (int nc = 0; nc < 8; ++nc) {
        int R = nc*16 + c;
        bf16x8 vf = *(const bf16x8*)&Vts[R*64 + (((ks*4 + g) ^ (R & 7)) * 8)];
        O[nc] = MFMA16(ks ? pa1 : pa0, vf, O[nc]);
      }
    }
  }

  short* ob = obf + ((size_t)(b*L_ + q0))*D_ + hh*HD_;
  #pragma unroll
  for (int r = 0; r < 4; ++r) {
    float inv = 1.f / lrun[r];
    #pragma unroll
    for (int nc = 0; nc < 8; ++nc)
      ob[(size_t)(g*4+r)*D_ + nc*16 + c] = f2bf(O[nc][r] * inv);
  }
}

// ---------------- heads ----------------
// lm partials: part[ks][j][VOCAB], ks=0..3 k-chunks, j=batch
__global__ __launch_bounds__(256) void lm_head_part_k(const float* __restrict__ h,
    const float* __restrict__ lm_w, float* __restrict__ part) {
  int tid = threadIdx.x;
  int n = (blockIdx.x*256 + tid)*4;
  int ks = blockIdx.y;
  __shared__ float last0[256], last1[256];
  const float* h0 = h + ((size_t)0*L_ + (L_-1))*D_ + ks*256;
  const float* h1 = h + ((size_t)1*L_ + (L_-1))*D_ + ks*256;
  last0[tid] = h0[tid]; last1[tid] = h1[tid];
  __syncthreads();
  float4 a0 = {0.f,0.f,0.f,0.f}, a1 = {0.f,0.f,0.f,0.f};
  const float* wp = lm_w + (size_t)(ks*256)*VOCAB_ + n;
  for (int kk = 0; kk < 256; ++kk) {
    float4 wv = *(const float4*)(wp + (size_t)kk*VOCAB_);
    float c0 = last0[kk], c1 = last1[kk];
    a0.x += c0*wv.x; a0.y += c0*wv.y; a0.z += c0*wv.z; a0.w += c0*wv.w;
    a1.x += c1*wv.x; a1.y += c1*wv.y; a1.z += c1*wv.z; a1.w += c1*wv.w;
  }
  *(float4*)(part + ((size_t)ks*2 + 0)*VOCAB_ + n) = a0;
  *(float4*)(part + ((size_t)ks*2 + 1)*VOCAB_ + n) = a1;
}

__global__ __launch_bounds__(256) void lm_head_red_k(const float* __restrict__ part,
    float* __restrict__ out) {
  int i = blockIdx.x*256 + threadIdx.x;        // over 2*VOCAB/4 float4s
  int j = (i*4) / VOCAB_;                      // 0 or 1 (batch)
  int n = (i*4) & (VOCAB_-1);
  float4 acc = {0.f,0.f,0.f,0.f};
  #pragma unroll
  for (int ks = 0; ks < 4; ++ks) {
    float4 v = *(const float4*)(part + ((size_t)ks*2 + j)*VOCAB_ + n);
    acc.x += v.x; acc.y += v.y; acc.z += v.z; acc.w += v.w;
  }
  *(float4*)(out + (size_t)j*VOCAB_ + n) = acc;
}

__global__ __launch_bounds__(128) void tool_head_k(const float* __restrict__ h,
    const float* __restrict__ tw, const float* __restrict__ tb, float* __restrict__ out) {
  int b = blockIdx.x;
  int tid = threadIdx.x;
  __shared__ float last[D_];
  const float* hr = h + ((size_t)b*L_ + (L_-1))*D_;
  for (int d = tid; d < D_; d += 128) last[d] = hr[d];
  __syncthreads();
  float acc = tb[tid];
  for (int k = 0; k < D_; ++k) acc += last[k]*tw[(size_t)k*TOOLV_ + tid];
  out[(size_t)2*VOCAB_ + (size_t)b*TOOLV_ + tid] = acc;
}

extern "C" void kernel_launch(void* const* d_in, const int* in_sizes, int n_in,
                              void* d_out, int out_size, void* d_ws, size_t ws_size,
                              hipStream_t stream) {
  const float* cs        = (const float*)d_in[1];
  const float* proj_w    = (const float*)d_in[2];
  const float* emb_scale = (const float*)d_in[3];
  const float* conv_dw_w = (const float*)d_in[4];
  const float* conv_dw_b = (const float*)d_in[5];
  const float* conv_pw_w = (const float*)d_in[6];
  const float* conv_pw_b = (const float*)d_in[7];
  const float* conv_ln_s = (const float*)d_in[8];
  const float* conv_ln_b = (const float*)d_in[9];
  const float* attn_q_w  = (const float*)d_in[10];
  const float* attn_kv_w = (const float*)d_in[11];
  const float* attn_out_w= (const float*)d_in[12];
  const float* attn_ln_s = (const float*)d_in[13];
  const float* attn_ln_b = (const float*)d_in[14];
  const float* lm_w      = (const float*)d_in[15];
  const float* tool_w    = (const float*)d_in[16];
  const float* tool_b    = (const float*)d_in[17];

  const int M = B_*L_;                              // 4096
  float* h    = (float*)d_ws;                       // M*D fp32
  float* buf2 = h    + (size_t)M*D_;                // M*2D fp32
  short* kbf  = (short*)(buf2 + (size_t)M*2*D_);    // B*H*L*128 bf16
  short* vtbf = kbf + (size_t)B_*HEADS_*L_*128;     // B*H*128*L bf16
  short* abf  = (short*)(vtbf + (size_t)B_*HEADS_*128*L_);  // M*D bf16
  short* wconv= abf + (size_t)M*D_;                 // 10 * 2D*D bf16
  short* wqkv = wconv + (size_t)NCONV_*2*D_*D_;     // 6 * 3D*D bf16
  short* wout = wqkv + (size_t)NATTN_*3*D_*D_;      // 6 * D*D bf16
  float* lmpart = (float*)(wout + (size_t)NATTN_*D_*D_);  // 4*2*VOCAB fp32
  short* qbf  = (short*)(buf2 + (size_t)M*D_);      // M*D bf16 (upper half of buf2)

  const float scale = 0.088388347648318447f;        // 128^-0.5

  // ---- batched weight prep (4 launches) ----
  {
    int n4 = NCONV_*2*D_*D_/4;
    cvt_bf16_k<<<(n4 + 255)/256, 256, 0, stream>>>(conv_pw_w, wconv, n4);
    transp_bf16_k<<<dim3(D_/32, D_/32, NATTN_), 256, 0, stream>>>(
        attn_q_w, wqkv, D_, D_, (size_t)D_*D_, (size_t)3*D_*D_);
    transp_bf16_k<<<dim3((2*D_)/32, D_/32, NATTN_), 256, 0, stream>>>(
        attn_kv_w, wqkv + (size_t)D_*D_, D_, 2*D_, (size_t)D_*2*D_, (size_t)3*D_*D_);
    transp_bf16_k<<<dim3(D_/32, D_/32, NATTN_), 256, 0, stream>>>(
        attn_out_w, wout, D_, D_, (size_t)D_*D_, (size_t)D_*D_);
  }

  julia_proj_k<<<M, 256, 0, stream>>>(cs, proj_w, emb_scale, h);

  for (int i = 0; i < NCONV_; ++i) {
    dwconv_k<<<(M*D_/4)/256, 256, 0, stream>>>(h, conv_dw_w + (size_t)i*D_*5,
                                               conv_dw_b + (size_t)i*D_, abf);
    gemm_bf16<0, true><<<dim3(M/128, (2*D_)/128), 256, 0, stream>>>(
        abf, wconv + (size_t)i*2*D_*D_, conv_pw_b + (size_t)i*2*D_,
        buf2, nullptr, nullptr, nullptr, 1.f, M, 2*D_, D_);
    glu_ln_k<<<M, 256, 0, stream>>>(h, buf2, conv_ln_s + (size_t)i*D_,
                                    conv_ln_b + (size_t)i*D_,
                                    (i == NCONV_-1) ? abf : (short*)nullptr);
  }

  for (int i = 0; i < NATTN_; ++i) {
    // abf holds bf16(h) from previous LN
    gemm_bf16<3, false><<<dim3(M/128, (3*D_)/128), 256, 0, stream>>>(
        abf, wqkv + (size_t)i*3*D_*D_, nullptr, nullptr, qbf, kbf, vtbf,
        scale, M, 3*D_, D_);
    attn2_k<<<dim3(L_/64, HEADS_, B_), 256, 0, stream>>>(qbf, kbf, vtbf, abf);
    gemm_bf16<0, false><<<dim3(M/128, D_/128), 256, 0, stream>>>(
        abf, wout + (size_t)i*D_*D_, nullptr, buf2, nullptr, nullptr, nullptr,
        1.f, M, D_, D_);
    resid_ln_k<<<M, 256, 0, stream>>>(h, buf2, attn_ln_s + (size_t)i*D_,
                                      attn_ln_b + (size_t)i*D_,
                                      (i < NATTN_-1) ? abf : (short*)nullptr);
  }

  lm_head_part_k<<<dim3(VOCAB_/1024, 4), 256, 0, stream>>>(h, lm_w, lmpart);
  lm_head_red_k<<<(2*VOCAB_/4)/256, 256, 0, stream>>>(lmpart, (float*)d_out);
  tool_head_k<<<B_, 128, 0, stream>>>(h, tool_w, tool_b, (float*)d_out);
}

// Round 7
// 1810.761 us; speedup vs baseline: 24.6593x; 1.0127x over previous
//
#include <hip/hip_runtime.h>
#include <hip/hip_bf16.h>
#include <math.h>

#define B_ 2
#define L_ 2048
#define D_ 1024
#define VOCAB_ 65536
#define TOOLV_ 128
#define NCONV_ 10
#define NATTN_ 6
#define HEADS_ 8
#define HD_ 128
#define EPS_ 1e-5f

typedef short bf16x8 __attribute__((ext_vector_type(8)));
typedef short short4v __attribute__((ext_vector_type(4)));
typedef float f32x4 __attribute__((ext_vector_type(4)));
#define MFMA16(a,b,c) __builtin_amdgcn_mfma_f32_16x16x32_bf16(a, b, c, 0, 0, 0)

__device__ inline short f2bf(float f) {
  __hip_bfloat16 h = __float2bfloat16(f);
  return *reinterpret_cast<short*>(&h);
}

__device__ __forceinline__ void gld16(const void* g, void* l) {
  __builtin_amdgcn_global_load_lds(
      (const __attribute__((address_space(1))) unsigned int*)g,
      (__attribute__((address_space(3))) unsigned int*)l, 16, 0, 0);
}

__device__ __forceinline__ void sync_prefetch() {
  asm volatile("s_waitcnt vmcnt(0)" ::: "memory");
  __builtin_amdgcn_s_barrier();
  __builtin_amdgcn_sched_barrier(0);
}

// ---------------- Julia feats + projection (float4) ----------------
__global__ __launch_bounds__(256) void julia_proj_k(const float* __restrict__ cs,
    const float* __restrict__ pw, const float* __restrict__ esc, float* __restrict__ h) {
  int row = blockIdx.x;                       // b*L + l
  float cr = cs[2*(size_t)row], ci = cs[2*(size_t)row+1];
  float f[16];
  float zr = 0.f, zi = 0.f;
  #pragma unroll
  for (int s = 0; s < 8; ++s) {
    float nzr = zr*zr - zi*zi + cr;
    float nzi = 2.f*zr*zi + ci;
    zr = nzr; zi = nzi;
    f[2*s] = zr; f[2*s+1] = zi;
  }
  float e = esc[0];
  int d = threadIdx.x * 4;
  float4 acc = {0.f, 0.f, 0.f, 0.f};
  #pragma unroll
  for (int i = 0; i < 16; ++i) {
    float4 pv = *(const float4*)(pw + i*D_ + d);
    acc.x += f[i]*pv.x; acc.y += f[i]*pv.y; acc.z += f[i]*pv.z; acc.w += f[i]*pv.w;
  }
  acc.x *= e; acc.y *= e; acc.z *= e; acc.w *= e;
  *(float4*)(h + (size_t)row*D_ + d) = acc;
}

// ---------------- depthwise conv over L (K=5, pad 2), float4, bf16 out ------
__global__ __launch_bounds__(256) void dwconv_k(const float* __restrict__ x,
    const float* __restrict__ w, const float* __restrict__ bias, short* __restrict__ y) {
  int idx = blockIdx.x*256 + threadIdx.x;              // over M * D/4
  int d = (idx & (D_/4 - 1)) * 4;
  int bl = idx >> 8;
  int l = bl & (L_-1);
  size_t bbase = (size_t)(bl >> 11) * L_;              // b*L
  float4 acc = *(const float4*)(bias + d);
  float wr[4][5];
  #pragma unroll
  for (int j = 0; j < 4; ++j)
    #pragma unroll
    for (int k = 0; k < 5; ++k) wr[j][k] = w[(d+j)*5 + k];
  #pragma unroll
  for (int k = 0; k < 5; ++k) {
    int ll = l + k - 2;
    if (ll >= 0 && ll < L_) {
      float4 xv = *(const float4*)(x + (bbase + ll)*D_ + d);
      acc.x += xv.x*wr[0][k]; acc.y += xv.y*wr[1][k];
      acc.z += xv.z*wr[2][k]; acc.w += xv.w*wr[3][k];
    }
  }
  short4v o = { f2bf(acc.x), f2bf(acc.y), f2bf(acc.z), f2bf(acc.w) };
  ((short4v*)y)[idx] = o;
}

// ---------------- bulk fp32 -> bf16 ----------------
__global__ __launch_bounds__(256) void cvt_bf16_k(const float* __restrict__ x,
    short* __restrict__ y, int n4) {
  int i = blockIdx.x*256 + threadIdx.x;
  if (i >= n4) return;
  float4 v = ((const float4*)x)[i];
  short4v s = { f2bf(v.x), f2bf(v.y), f2bf(v.z), f2bf(v.w) };
  ((short4v*)y)[i] = s;
}

// (K,N) fp32 -> (N,K) bf16 transpose, batched over blockIdx.z layers
__global__ __launch_bounds__(256) void transp_bf16_k(const float* __restrict__ W0,
    short* __restrict__ WT0, int K, int N, size_t srcStride, size_t dstStride) {
  const float* W = W0 + blockIdx.z*srcStride;
  short* WT = WT0 + blockIdx.z*dstStride;
  __shared__ short t[32][33];
  int n0 = blockIdx.x*32, k0 = blockIdx.y*32;
  int tx = threadIdx.x & 31, ty = threadIdx.x >> 5;   // ty 0..7
  #pragma unroll
  for (int i = 0; i < 4; ++i) {
    int k = ty + i*8;
    t[tx][k] = f2bf(W[(size_t)(k0+k)*N + n0 + tx]);
  }
  __syncthreads();
  #pragma unroll
  for (int i = 0; i < 4; ++i) {
    int n = ty + i*8;
    WT[(size_t)(n0+n)*K + k0 + tx] = t[n][tx];
  }
}

// ---------------- bf16 MFMA GEMM: A(M,K)bf16 x Bt(N,K)bf16 -----
// 128x128 tile, BK=32, double-buffered LDS with issue-early prefetch:
// stage(t+1) -> compute(t) -> vmcnt(0)+raw barrier.  One barrier per K-tile.
// MODE 0: fp32 C (+bias).  MODE 3: fused QKV epilogue.
template<int MODE, bool BIAS>
__global__ __launch_bounds__(256) void gemm_bf16(const short* __restrict__ A,
    const short* __restrict__ Bt, const float* __restrict__ bias,
    float* __restrict__ C, short* __restrict__ obf,
    short* __restrict__ kbf, short* __restrict__ vtbf,
    float scale, int M, int N, int K) {
  __shared__ short As[2][128*32];
  __shared__ short Bs[2][128*32];
  const int tid  = threadIdx.x;
  const int lane = tid & 63;
  const int wave = tid >> 6;
  const int wm = wave >> 1, wn = wave & 1;
  const int g = lane >> 4, c = lane & 15;
  const int m0 = blockIdx.x * 128, n0 = blockIdx.y * 128;

  f32x4 acc[4][4];
  #pragma unroll
  for (int i = 0; i < 4; ++i)
    #pragma unroll
    for (int j = 0; j < 4; ++j) acc[i][j] = (f32x4){0.f,0.f,0.f,0.f};

  const int srow = wave*16 + (lane>>2);
  const int scol = (lane&3)*8;
  const short* aSrc0 = A + (size_t)(m0 + srow)*K + scol;
  const short* aSrc1 = aSrc0 + (size_t)64*K;
  const short* bSrc0 = Bt + (size_t)(n0 + srow)*K + scol;
  const short* bSrc1 = bSrc0 + (size_t)64*K;
  const int woff = wave*512;

  // prologue: stage tile 0 into buffer 0
  gld16(aSrc0, &As[0][woff]);
  gld16(aSrc1, &As[0][woff + 2048]);
  gld16(bSrc0, &Bs[0][woff]);
  gld16(bSrc1, &Bs[0][woff + 2048]);
  sync_prefetch();

  const int nt = K >> 5;
  int cur = 0;
  for (int t = 0; t < nt; ++t) {
    if (t + 1 < nt) {                       // issue next tile BEFORE compute
      int k0 = (t + 1) << 5;
      gld16(aSrc0 + k0, &As[cur^1][woff]);
      gld16(aSrc1 + k0, &As[cur^1][woff + 2048]);
      gld16(bSrc0 + k0, &Bs[cur^1][woff]);
      gld16(bSrc1 + k0, &Bs[cur^1][woff + 2048]);
    }
    bf16x8 af[4], bfr[4];
    #pragma unroll
    for (int mi = 0; mi < 4; ++mi)
      af[mi] = *(const bf16x8*)&As[cur][(wm*64 + mi*16 + c)*32 + g*8];
    #pragma unroll
    for (int ni = 0; ni < 4; ++ni)
      bfr[ni] = *(const bf16x8*)&Bs[cur][(wn*64 + ni*16 + c)*32 + g*8];
    #pragma unroll
    for (int mi = 0; mi < 4; ++mi)
      #pragma unroll
      for (int ni = 0; ni < 4; ++ni)
        acc[mi][ni] = MFMA16(af[mi], bfr[ni], acc[mi][ni]);
    if (t + 1 < nt) {
      sync_prefetch();                      // next tile resident, LDS free
      cur ^= 1;
    }
  }

  #pragma unroll
  for (int mi = 0; mi < 4; ++mi) {
    int row = m0 + wm*64 + mi*16 + g*4;
    #pragma unroll
    for (int ni = 0; ni < 4; ++ni) {
      int col = n0 + wn*64 + ni*16 + c;
      if (MODE == 0) {
        float bv = BIAS ? bias[col] : 0.f;
        #pragma unroll
        for (int r = 0; r < 4; ++r)
          C[(size_t)(row+r)*N + col] = acc[mi][ni][r] + bv;
      } else {  // MODE 3
        if (col < 1024) {
          #pragma unroll
          for (int r = 0; r < 4; ++r)
            obf[(size_t)(row+r)*1024 + col] = f2bf(acc[mi][ni][r]*scale);
        } else {
          int col2 = col - 1024;
          int hh = col2 >> 8, jj = (col2 >> 7) & 1, d = col2 & 127;
          int bb = row >> 11, l = row & 2047;
          size_t bh = (size_t)bb*8 + hh;
          if (jj == 0) {
            #pragma unroll
            for (int r = 0; r < 4; ++r)
              kbf[(bh*L_ + l + r)*128 + d] = f2bf(acc[mi][ni][r]);
          } else {
            #pragma unroll
            for (int r = 0; r < 4; ++r)
              vtbf[(bh*128 + d)*L_ + l + r] = f2bf(acc[mi][ni][r]);
          }
        }
      }
    }
  }
}

// ---------------- GLU + residual + LayerNorm (float4, regs, opt bf16 out) ----
__global__ __launch_bounds__(256) void glu_ln_k(float* __restrict__ h,
    const float* __restrict__ y2, const float* __restrict__ s, const float* __restrict__ b,
    short* __restrict__ bo) {
  int row = blockIdx.x;
  int tid = threadIdx.x;
  int d = tid*4;
  float* xr = h + (size_t)row*D_;
  const float* yr = y2 + (size_t)row*2*D_;
  __shared__ float red[256];
  float4 xv = *(const float4*)(xr + d);
  float4 av = *(const float4*)(yr + d);
  float4 gv = *(const float4*)(yr + D_ + d);
  float v[4];
  v[0] = xv.x + av.x/(1.f + expf(-gv.x));
  v[1] = xv.y + av.y/(1.f + expf(-gv.y));
  v[2] = xv.z + av.z/(1.f + expf(-gv.z));
  v[3] = xv.w + av.w/(1.f + expf(-gv.w));
  red[tid] = v[0]+v[1]+v[2]+v[3]; __syncthreads();
  for (int st = 128; st > 0; st >>= 1) { if (tid < st) red[tid] += red[tid+st]; __syncthreads(); }
  float mu = red[0] * (1.f/D_); __syncthreads();
  float lv = 0.f;
  #pragma unroll
  for (int j = 0; j < 4; ++j) { float dd = v[j]-mu; lv += dd*dd; }
  red[tid] = lv; __syncthreads();
  for (int st = 128; st > 0; st >>= 1) { if (tid < st) red[tid] += red[tid+st]; __syncthreads(); }
  float var = red[0] * (1.f/D_);
  float r = 1.f/sqrtf(var + EPS_);
  float4 sv = *(const float4*)(s + d);
  float4 bv = *(const float4*)(b + d);
  float4 o;
  o.x = (v[0]-mu)*r*sv.x + bv.x;
  o.y = (v[1]-mu)*r*sv.y + bv.y;
  o.z = (v[2]-mu)*r*sv.z + bv.z;
  o.w = (v[3]-mu)*r*sv.w + bv.w;
  *(float4*)(xr + d) = o;
  if (bo) {
    short4v ob = { f2bf(o.x), f2bf(o.y), f2bf(o.z), f2bf(o.w) };
    *(short4v*)(bo + (size_t)row*D_ + d) = ob;
  }
}

// ---------------- residual + LayerNorm (float4, regs, opt bf16 out) ----------
__global__ __launch_bounds__(256) void resid_ln_k(float* __restrict__ h,
    const float* __restrict__ proj, const float* __restrict__ s, const float* __restrict__ b,
    short* __restrict__ bo) {
  int row = blockIdx.x;
  int tid = threadIdx.x;
  int d = tid*4;
  float* xr = h + (size_t)row*D_;
  const float* pr = proj + (size_t)row*D_;
  __shared__ float red[256];
  float4 xv = *(const float4*)(xr + d);
  float4 pv = *(const float4*)(pr + d);
  float v[4] = { xv.x+pv.x, xv.y+pv.y, xv.z+pv.z, xv.w+pv.w };
  red[tid] = v[0]+v[1]+v[2]+v[3]; __syncthreads();
  for (int st = 128; st > 0; st >>= 1) { if (tid < st) red[tid] += red[tid+st]; __syncthreads(); }
  float mu = red[0] * (1.f/D_); __syncthreads();
  float lv = 0.f;
  #pragma unroll
  for (int j = 0; j < 4; ++j) { float dd = v[j]-mu; lv += dd*dd; }
  red[tid] = lv; __syncthreads();
  for (int st = 128; st > 0; st >>= 1) { if (tid < st) red[tid] += red[tid+st]; __syncthreads(); }
  float var = red[0] * (1.f/D_);
  float r = 1.f/sqrtf(var + EPS_);
  float4 sv = *(const float4*)(s + d);
  float4 bv = *(const float4*)(b + d);
  float4 o;
  o.x = (v[0]-mu)*r*sv.x + bv.x;
  o.y = (v[1]-mu)*r*sv.y + bv.y;
  o.z = (v[2]-mu)*r*sv.z + bv.z;
  o.w = (v[3]-mu)*r*sv.w + bv.w;
  *(float4*)(xr + d) = o;
  if (bo) {
    short4v ob = { f2bf(o.x), f2bf(o.y), f2bf(o.z), f2bf(o.w) };
    *(short4v*)(bo + (size_t)row*D_ + d) = ob;
  }
}

// ---------------- flash attention: bf16 in, swizzled dbuf LDS, prefetch ------
#define PPITCH 72
__global__ __launch_bounds__(256) void attn2_k(const short* __restrict__ qbf,
    const short* __restrict__ kbf, const short* __restrict__ vtbf,
    short* __restrict__ obf) {
  __shared__ short Ks[2][64*128];   // [kv 64][d 128] swizzled 16B blocks
  __shared__ short Vts[2][128*64];  // [d 128][kv 64] swizzled 16B blocks
  __shared__ short Ps[4*16*PPITCH];

  const int tid  = threadIdx.x;
  const int wave = tid >> 6;
  const int lane = tid & 63;
  const int g    = lane >> 4;
  const int c    = lane & 15;
  const int hh   = blockIdx.y;
  const int b    = blockIdx.z;
  const int q0   = blockIdx.x*64 + wave*16;
  const size_t bh = (size_t)(b*HEADS_ + hh);

  bf16x8 qf[4];
  {
    const short* Qp = qbf + ((size_t)(b*L_ + q0 + c))*D_ + hh*HD_;
    #pragma unroll
    for (int kd = 0; kd < 4; ++kd)
      qf[kd] = *(const bf16x8*)(Qp + kd*32 + g*8);
  }

  f32x4 O[8];
  #pragma unroll
  for (int i = 0; i < 8; ++i) O[i] = (f32x4){0.f,0.f,0.f,0.f};
  float mrun[4] = {-INFINITY,-INFINITY,-INFINITY,-INFINITY};
  float lrun[4] = {0.f,0.f,0.f,0.f};
  short* Pw = Ps + wave*16*PPITCH;

  const short* kBase = kbf + bh*L_*128;
  const short* vBase = vtbf + bh*128*L_;

  // staging helper (4 K + 4 V gld16 per thread)
  auto stage = [&](int t, int buf) {
    #pragma unroll
    for (int rd = 0; rd < 4; ++rd) {
      int slot = rd*256 + tid;
      int kr = slot >> 4, kj = slot & 15;
      int vr = slot >> 3, vj = slot & 7;
      gld16(kBase + ((size_t)(t*64 + kr))*128 + ((kj ^ (kr & 15)) * 8),
            (char*)&Ks[buf][0] + (rd*256 + wave*64)*16);
      gld16(vBase + (size_t)vr*L_ + t*64 + ((vj ^ (vr & 7)) * 8),
            (char*)&Vts[buf][0] + (rd*256 + wave*64)*16);
    }
  };

  stage(0, 0);
  sync_prefetch();
  int cur = 0;
  const int NT = L_/64;

  for (int t = 0; t < NT; ++t) {
    if (t + 1 < NT) stage(t + 1, cur^1);    // issue-early

    f32x4 s[4];
    #pragma unroll
    for (int nc = 0; nc < 4; ++nc) {
      s[nc] = (f32x4){0.f,0.f,0.f,0.f};
      int R = nc*16 + c;
      #pragma unroll
      for (int kd = 0; kd < 4; ++kd) {
        bf16x8 kf = *(const bf16x8*)&Ks[cur][R*128 + (((kd*4 + g) ^ (R & 15)) * 8)];
        s[nc] = MFMA16(qf[kd], kf, s[nc]);
      }
    }

    float tm[4], rsum[4], alpha[4];
    #pragma unroll
    for (int r = 0; r < 4; ++r)
      tm[r] = fmaxf(fmaxf(s[0][r], s[1][r]), fmaxf(s[2][r], s[3][r]));
    #pragma unroll
    for (int r = 0; r < 4; ++r) {
      #pragma unroll
      for (int mask = 1; mask <= 8; mask <<= 1)
        tm[r] = fmaxf(tm[r], __shfl_xor(tm[r], mask));
      float mnew = fmaxf(mrun[r], tm[r]);
      alpha[r] = expf(mrun[r] - mnew);
      mrun[r] = mnew;
      rsum[r] = 0.f;
    }
    #pragma unroll
    for (int nc = 0; nc < 4; ++nc)
      #pragma unroll
      for (int r = 0; r < 4; ++r) {
        float p = expf(s[nc][r] - mrun[r]);
        s[nc][r] = p;
        rsum[r] += p;
      }
    #pragma unroll
    for (int r = 0; r < 4; ++r) {
      #pragma unroll
      for (int mask = 1; mask <= 8; mask <<= 1)
        rsum[r] += __shfl_xor(rsum[r], mask);
      lrun[r] = lrun[r]*alpha[r] + rsum[r];
    }
    #pragma unroll
    for (int nc = 0; nc < 8; ++nc)
      #pragma unroll
      for (int r = 0; r < 4; ++r) O[nc][r] *= alpha[r];

    #pragma unroll
    for (int nc = 0; nc < 4; ++nc)
      #pragma unroll
      for (int r = 0; r < 4; ++r)
        Pw[(g*4+r)*PPITCH + nc*16 + c] = f2bf(s[nc][r]);
    asm volatile("s_waitcnt lgkmcnt(0)" ::: "memory");
    bf16x8 pa0 = *(const bf16x8*)&Pw[c*PPITCH + g*8];
    bf16x8 pa1 = *(const bf16x8*)&Pw[c*PPITCH + 32 + g*8];

    #pragma unroll
    for (int ks = 0; ks < 2; ++ks) {
      #pragma unroll
      for (int nc = 0; nc < 8; ++nc) {
        int R = nc*16 + c;
        bf16x8 vf = *(const bf16x8*)&Vts[cur][R*64 + (((ks*4 + g) ^ (R & 7)) * 8)];
        O[nc] = MFMA16(ks ? pa1 : pa0, vf, O[nc]);
      }
    }

    if (t + 1 < NT) {
      sync_prefetch();
      cur ^= 1;
    }
  }

  short* ob = obf + ((size_t)(b*L_ + q0))*D_ + hh*HD_;
  #pragma unroll
  for (int r = 0; r < 4; ++r) {
    float inv = 1.f / lrun[r];
    #pragma unroll
    for (int nc = 0; nc < 8; ++nc)
      ob[(size_t)(g*4+r)*D_ + nc*16 + c] = f2bf(O[nc][r] * inv);
  }
}

// ---------------- heads ----------------
// lm partials: part[ks][j][VOCAB], ks=0..3 k-chunks, j=batch
__global__ __launch_bounds__(256) void lm_head_part_k(const float* __restrict__ h,
    const float* __restrict__ lm_w, float* __restrict__ part) {
  int tid = threadIdx.x;
  int n = (blockIdx.x*256 + tid)*4;
  int ks = blockIdx.y;
  __shared__ float last0[256], last1[256];
  const float* h0 = h + ((size_t)0*L_ + (L_-1))*D_ + ks*256;
  const float* h1 = h + ((size_t)1*L_ + (L_-1))*D_ + ks*256;
  last0[tid] = h0[tid]; last1[tid] = h1[tid];
  __syncthreads();
  float4 a0 = {0.f,0.f,0.f,0.f}, a1 = {0.f,0.f,0.f,0.f};
  const float* wp = lm_w + (size_t)(ks*256)*VOCAB_ + n;
  for (int kk = 0; kk < 256; ++kk) {
    float4 wv = *(const float4*)(wp + (size_t)kk*VOCAB_);
    float c0 = last0[kk], c1 = last1[kk];
    a0.x += c0*wv.x; a0.y += c0*wv.y; a0.z += c0*wv.z; a0.w += c0*wv.w;
    a1.x += c1*wv.x; a1.y += c1*wv.y; a1.z += c1*wv.z; a1.w += c1*wv.w;
  }
  *(float4*)(part + ((size_t)ks*2 + 0)*VOCAB_ + n) = a0;
  *(float4*)(part + ((size_t)ks*2 + 1)*VOCAB_ + n) = a1;
}

__global__ __launch_bounds__(256) void lm_head_red_k(const float* __restrict__ part,
    float* __restrict__ out) {
  int i = blockIdx.x*256 + threadIdx.x;        // over 2*VOCAB/4 float4s
  int j = (i*4) / VOCAB_;                      // 0 or 1 (batch)
  int n = (i*4) & (VOCAB_-1);
  float4 acc = {0.f,0.f,0.f,0.f};
  #pragma unroll
  for (int ks = 0; ks < 4; ++ks) {
    float4 v = *(const float4*)(part + ((size_t)ks*2 + j)*VOCAB_ + n);
    acc.x += v.x; acc.y += v.y; acc.z += v.z; acc.w += v.w;
  }
  *(float4*)(out + (size_t)j*VOCAB_ + n) = acc;
}

__global__ __launch_bounds__(128) void tool_head_k(const float* __restrict__ h,
    const float* __restrict__ tw, const float* __restrict__ tb, float* __restrict__ out) {
  int b = blockIdx.x;
  int tid = threadIdx.x;
  __shared__ float last[D_];
  const float* hr = h + ((size_t)b*L_ + (L_-1))*D_;
  for (int d = tid; d < D_; d += 128) last[d] = hr[d];
  __syncthreads();
  float acc = tb[tid];
  for (int k = 0; k < D_; ++k) acc += last[k]*tw[(size_t)k*TOOLV_ + tid];
  out[(size_t)2*VOCAB_ + (size_t)b*TOOLV_ + tid] = acc;
}

extern "C" void kernel_launch(void* const* d_in, const int* in_sizes, int n_in,
                              void* d_out, int out_size, void* d_ws, size_t ws_size,
                              hipStream_t stream) {
  const float* cs        = (const float*)d_in[1];
  const float* proj_w    = (const float*)d_in[2];
  const float* emb_scale = (const float*)d_in[3];
  const float* conv_dw_w = (const float*)d_in[4];
  const float* conv_dw_b = (const float*)d_in[5];
  const float* conv_pw_w = (const float*)d_in[6];
  const float* conv_pw_b = (const float*)d_in[7];
  const float* conv_ln_s = (const float*)d_in[8];
  const float* conv_ln_b = (const float*)d_in[9];
  const float* attn_q_w  = (const float*)d_in[10];
  const float* attn_kv_w = (const float*)d_in[11];
  const float* attn_out_w= (const float*)d_in[12];
  const float* attn_ln_s = (const float*)d_in[13];
  const float* attn_ln_b = (const float*)d_in[14];
  const float* lm_w      = (const float*)d_in[15];
  const float* tool_w    = (const float*)d_in[16];
  const float* tool_b    = (const float*)d_in[17];

  const int M = B_*L_;                              // 4096
  float* h    = (float*)d_ws;                       // M*D fp32
  float* buf2 = h    + (size_t)M*D_;                // M*2D fp32
  short* kbf  = (short*)(buf2 + (size_t)M*2*D_);    // B*H*L*128 bf16
  short* vtbf = kbf + (size_t)B_*HEADS_*L_*128;     // B*H*128*L bf16
  short* abf  = (short*)(vtbf + (size_t)B_*HEADS_*128*L_);  // M*D bf16
  short* wconv= abf + (size_t)M*D_;                 // 10 * 2D*D bf16
  short* wqkv = wconv + (size_t)NCONV_*2*D_*D_;     // 6 * 3D*D bf16
  short* wout = wqkv + (size_t)NATTN_*3*D_*D_;      // 6 * D*D bf16
  float* lmpart = (float*)(wout + (size_t)NATTN_*D_*D_);  // 4*2*VOCAB fp32
  short* qbf  = (short*)(buf2 + (size_t)M*D_);      // M*D bf16 (upper half of buf2)

  const float scale = 0.088388347648318447f;        // 128^-0.5

  // ---- batched weight prep (4 launches) ----
  {
    int n4 = NCONV_*2*D_*D_/4;
    cvt_bf16_k<<<(n4 + 255)/256, 256, 0, stream>>>(conv_pw_w, wconv, n4);
    transp_bf16_k<<<dim3(D_/32, D_/32, NATTN_), 256, 0, stream>>>(
        attn_q_w, wqkv, D_, D_, (size_t)D_*D_, (size_t)3*D_*D_);
    transp_bf16_k<<<dim3((2*D_)/32, D_/32, NATTN_), 256, 0, stream>>>(
        attn_kv_w, wqkv + (size_t)D_*D_, D_, 2*D_, (size_t)D_*2*D_, (size_t)3*D_*D_);
    transp_bf16_k<<<dim3(D_/32, D_/32, NATTN_), 256, 0, stream>>>(
        attn_out_w, wout, D_, D_, (size_t)D_*D_, (size_t)D_*D_);
  }

  julia_proj_k<<<M, 256, 0, stream>>>(cs, proj_w, emb_scale, h);

  for (int i = 0; i < NCONV_; ++i) {
    dwconv_k<<<(M*D_/4)/256, 256, 0, stream>>>(h, conv_dw_w + (size_t)i*D_*5,
                                               conv_dw_b + (size_t)i*D_, abf);
    gemm_bf16<0, true><<<dim3(M/128, (2*D_)/128), 256, 0, stream>>>(
        abf, wconv + (size_t)i*2*D_*D_, conv_pw_b + (size_t)i*2*D_,
        buf2, nullptr, nullptr, nullptr, 1.f, M, 2*D_, D_);
    glu_ln_k<<<M, 256, 0, stream>>>(h, buf2, conv_ln_s + (size_t)i*D_,
                                    conv_ln_b + (size_t)i*D_,
                                    (i == NCONV_-1) ? abf : (short*)nullptr);
  }

  for (int i = 0; i < NATTN_; ++i) {
    // abf holds bf16(h) from previous LN
    gemm_bf16<3, false><<<dim3(M/128, (3*D_)/128), 256, 0, stream>>>(
        abf, wqkv + (size_t)i*3*D_*D_, nullptr, nullptr, qbf, kbf, vtbf,
        scale, M, 3*D_, D_);
    attn2_k<<<dim3(L_/64, HEADS_, B_), 256, 0, stream>>>(qbf, kbf, vtbf, abf);
    gemm_bf16<0, false><<<dim3(M/128, D_/128), 256, 0, stream>>>(
        abf, wout + (size_t)i*D_*D_, nullptr, buf2, nullptr, nullptr, nullptr,
        1.f, M, D_, D_);
    resid_ln_k<<<M, 256, 0, stream>>>(h, buf2, attn_ln_s + (size_t)i*D_,
                                      attn_ln_b + (size_t)i*D_,
                                      (i < NATTN_-1) ? abf : (short*)nullptr);
  }

  lm_head_part_k<<<dim3(VOCAB_/1024, 4), 256, 0, stream>>>(h, lm_w, lmpart);
  lm_head_red_k<<<(2*VOCAB_/4)/256, 256, 0, stream>>>(lmpart, (float*)d_out);
  tool_head_k<<<B_, 128, 0, stream>>>(h, tool_w, tool_b, (float*)d_out);
}

// Round 8
// 1800.739 us; speedup vs baseline: 24.7966x; 1.0056x over previous
//
#include <hip/hip_runtime.h>
#include <hip/hip_bf16.h>
#include <math.h>

#define B_ 2
#define L_ 2048
#define D_ 1024
#define VOCAB_ 65536
#define TOOLV_ 128
#define NCONV_ 10
#define NATTN_ 6
#define HEADS_ 8
#define HD_ 128
#define EPS_ 1e-5f

typedef short bf16x8 __attribute__((ext_vector_type(8)));
typedef short short4v __attribute__((ext_vector_type(4)));
typedef float f32x4 __attribute__((ext_vector_type(4)));
#define MFMA16(a,b,c) __builtin_amdgcn_mfma_f32_16x16x32_bf16(a, b, c, 0, 0, 0)

__device__ inline short f2bf(float f) {
  __hip_bfloat16 h = __float2bfloat16(f);
  return *reinterpret_cast<short*>(&h);
}

__device__ __forceinline__ void gld16(const void* g, void* l) {
  __builtin_amdgcn_global_load_lds(
      (const __attribute__((address_space(1))) unsigned int*)g,
      (__attribute__((address_space(3))) unsigned int*)l, 16, 0, 0);
}

__device__ __forceinline__ void sync_prefetch() {
  asm volatile("s_waitcnt vmcnt(0)" ::: "memory");
  __builtin_amdgcn_s_barrier();
  __builtin_amdgcn_sched_barrier(0);
}

// ---------------- Julia feats + projection (float4) ----------------
__global__ __launch_bounds__(256) void julia_proj_k(const float* __restrict__ cs,
    const float* __restrict__ pw, const float* __restrict__ esc, float* __restrict__ h) {
  int row = blockIdx.x;                       // b*L + l
  float cr = cs[2*(size_t)row], ci = cs[2*(size_t)row+1];
  float f[16];
  float zr = 0.f, zi = 0.f;
  #pragma unroll
  for (int s = 0; s < 8; ++s) {
    float nzr = zr*zr - zi*zi + cr;
    float nzi = 2.f*zr*zi + ci;
    zr = nzr; zi = nzi;
    f[2*s] = zr; f[2*s+1] = zi;
  }
  float e = esc[0];
  int d = threadIdx.x * 4;
  float4 acc = {0.f, 0.f, 0.f, 0.f};
  #pragma unroll
  for (int i = 0; i < 16; ++i) {
    float4 pv = *(const float4*)(pw + i*D_ + d);
    acc.x += f[i]*pv.x; acc.y += f[i]*pv.y; acc.z += f[i]*pv.z; acc.w += f[i]*pv.w;
  }
  acc.x *= e; acc.y *= e; acc.z *= e; acc.w *= e;
  *(float4*)(h + (size_t)row*D_ + d) = acc;
}

// ---------------- depthwise conv over L (K=5, pad 2), float4, bf16 out ------
__global__ __launch_bounds__(256) void dwconv_k(const float* __restrict__ x,
    const float* __restrict__ w, const float* __restrict__ bias, short* __restrict__ y) {
  int idx = blockIdx.x*256 + threadIdx.x;              // over M * D/4
  int d = (idx & (D_/4 - 1)) * 4;
  int bl = idx >> 8;
  int l = bl & (L_-1);
  size_t bbase = (size_t)(bl >> 11) * L_;              // b*L
  float4 acc = *(const float4*)(bias + d);
  float wr[4][5];
  #pragma unroll
  for (int j = 0; j < 4; ++j)
    #pragma unroll
    for (int k = 0; k < 5; ++k) wr[j][k] = w[(d+j)*5 + k];
  #pragma unroll
  for (int k = 0; k < 5; ++k) {
    int ll = l + k - 2;
    if (ll >= 0 && ll < L_) {
      float4 xv = *(const float4*)(x + (bbase + ll)*D_ + d);
      acc.x += xv.x*wr[0][k]; acc.y += xv.y*wr[1][k];
      acc.z += xv.z*wr[2][k]; acc.w += xv.w*wr[3][k];
    }
  }
  short4v o = { f2bf(acc.x), f2bf(acc.y), f2bf(acc.z), f2bf(acc.w) };
  ((short4v*)y)[idx] = o;
}

// ---------------- conv pw weight: fp32 (N,K) -> bf16 permuted (N,K) ----------
// pi(r): t=r>>7, wn=(r>>6)&1, j=r&63; u=t*64+wn*32+(j&31); src=(j<32)?u:1024+u
__global__ __launch_bounds__(256) void cvt_perm_k(const float* __restrict__ W,
    short* __restrict__ out) {
  int z = blockIdx.y;
  int i4 = blockIdx.x*256 + threadIdx.x;       // float4 idx within layer
  int e = i4*4;
  int r = e >> 10, k = e & 1023;
  int t = r >> 7, wn = (r >> 6) & 1, j = r & 63;
  int u = t*64 + wn*32 + (j & 31);
  int src = (j < 32) ? u : 1024 + u;
  const float* p = W + ((size_t)z*2048 + src)*1024 + k;
  float4 v = *(const float4*)p;
  short4v s = { f2bf(v.x), f2bf(v.y), f2bf(v.z), f2bf(v.w) };
  *(short4v*)(out + ((size_t)z*2048 + r)*1024 + k) = s;
}

// (K,N) fp32 -> (N,K) bf16 transpose, batched over blockIdx.z layers
__global__ __launch_bounds__(256) void transp_bf16_k(const float* __restrict__ W0,
    short* __restrict__ WT0, int K, int N, size_t srcStride, size_t dstStride) {
  const float* W = W0 + blockIdx.z*srcStride;
  short* WT = WT0 + blockIdx.z*dstStride;
  __shared__ short t[32][33];
  int n0 = blockIdx.x*32, k0 = blockIdx.y*32;
  int tx = threadIdx.x & 31, ty = threadIdx.x >> 5;   // ty 0..7
  #pragma unroll
  for (int i = 0; i < 4; ++i) {
    int k = ty + i*8;
    t[tx][k] = f2bf(W[(size_t)(k0+k)*N + n0 + tx]);
  }
  __syncthreads();
  #pragma unroll
  for (int i = 0; i < 4; ++i) {
    int n = ty + i*8;
    WT[(size_t)(n0+n)*K + k0 + tx] = t[n][tx];
  }
}

// ---------------- bf16 MFMA GEMM: A(M,K)bf16 x Bt(N,K)bf16 -----
// 128x128 tile, BK=32 dbuf + issue-early prefetch, XCD-chunked block swizzle.
// MODE 0: fp32 C.  MODE 3: fused QKV epilogue.  MODE 4: fused GLU (permuted B),
//         writes C (M x 1024) fp32 = a*sigmoid(gate).
template<int MODE>
__global__ __launch_bounds__(256) void gemm_bf16(const short* __restrict__ A,
    const short* __restrict__ Bt, const float* __restrict__ bias,
    float* __restrict__ C, short* __restrict__ obf,
    short* __restrict__ kbf, short* __restrict__ vtbf,
    float scale, int M, int N, int K) {
  __shared__ short As[2][128*32];
  __shared__ short Bs[2][128*32];
  const int tid  = threadIdx.x;
  const int lane = tid & 63;
  const int wave = tid >> 6;
  const int wm = wave >> 1, wn = wave & 1;
  const int g = lane >> 4, c = lane & 15;

  // XCD-chunked bijective swizzle (gridDim.x = 32 always; nwg % 8 == 0)
  int flat = blockIdx.y * gridDim.x + blockIdx.x;
  int nwg  = gridDim.x * gridDim.y;
  int swz  = (flat & 7) * (nwg >> 3) + (flat >> 3);
  const int m0 = (swz & 31) * 128;
  const int n0 = (swz >> 5) * 128;

  f32x4 acc[4][4];
  #pragma unroll
  for (int i = 0; i < 4; ++i)
    #pragma unroll
    for (int j = 0; j < 4; ++j) acc[i][j] = (f32x4){0.f,0.f,0.f,0.f};

  const int srow = wave*16 + (lane>>2);
  const int scol = (lane&3)*8;
  const short* aSrc0 = A + (size_t)(m0 + srow)*K + scol;
  const short* aSrc1 = aSrc0 + (size_t)64*K;
  const short* bSrc0 = Bt + (size_t)(n0 + srow)*K + scol;
  const short* bSrc1 = bSrc0 + (size_t)64*K;
  const int woff = wave*512;

  gld16(aSrc0, &As[0][woff]);
  gld16(aSrc1, &As[0][woff + 2048]);
  gld16(bSrc0, &Bs[0][woff]);
  gld16(bSrc1, &Bs[0][woff + 2048]);
  sync_prefetch();

  const int nt = K >> 5;
  int cur = 0;
  for (int t = 0; t < nt; ++t) {
    if (t + 1 < nt) {
      int k0 = (t + 1) << 5;
      gld16(aSrc0 + k0, &As[cur^1][woff]);
      gld16(aSrc1 + k0, &As[cur^1][woff + 2048]);
      gld16(bSrc0 + k0, &Bs[cur^1][woff]);
      gld16(bSrc1 + k0, &Bs[cur^1][woff + 2048]);
    }
    bf16x8 af[4], bfr[4];
    #pragma unroll
    for (int mi = 0; mi < 4; ++mi)
      af[mi] = *(const bf16x8*)&As[cur][(wm*64 + mi*16 + c)*32 + g*8];
    #pragma unroll
    for (int ni = 0; ni < 4; ++ni)
      bfr[ni] = *(const bf16x8*)&Bs[cur][(wn*64 + ni*16 + c)*32 + g*8];
    #pragma unroll
    for (int mi = 0; mi < 4; ++mi)
      #pragma unroll
      for (int ni = 0; ni < 4; ++ni)
        acc[mi][ni] = MFMA16(af[mi], bfr[ni], acc[mi][ni]);
    if (t + 1 < nt) {
      sync_prefetch();
      cur ^= 1;
    }
  }

  if (MODE == 4) {
    // permuted cols: pair (a, gate) sits at (ni, ni+2); output col u in [0,1024)
    #pragma unroll
    for (int mi = 0; mi < 4; ++mi) {
      int row = m0 + wm*64 + mi*16 + g*4;
      #pragma unroll
      for (int ni = 0; ni < 2; ++ni) {
        int u = (n0 >> 7)*64 + wn*32 + ni*16 + c;
        float ba = bias[u], bg = bias[1024 + u];
        #pragma unroll
        for (int r = 0; r < 4; ++r) {
          float a  = acc[mi][ni][r]   + ba;
          float gt = acc[mi][ni+2][r] + bg;
          C[(size_t)(row+r)*1024 + u] = a / (1.f + expf(-gt));
        }
      }
    }
    return;
  }

  #pragma unroll
  for (int mi = 0; mi < 4; ++mi) {
    int row = m0 + wm*64 + mi*16 + g*4;
    #pragma unroll
    for (int ni = 0; ni < 4; ++ni) {
      int col = n0 + wn*64 + ni*16 + c;
      if (MODE == 0) {
        #pragma unroll
        for (int r = 0; r < 4; ++r)
          C[(size_t)(row+r)*N + col] = acc[mi][ni][r];
      } else {  // MODE 3
        if (col < 1024) {
          #pragma unroll
          for (int r = 0; r < 4; ++r)
            obf[(size_t)(row+r)*1024 + col] = f2bf(acc[mi][ni][r]*scale);
        } else {
          int col2 = col - 1024;
          int hh = col2 >> 8, jj = (col2 >> 7) & 1, d = col2 & 127;
          int bb = row >> 11, l = row & 2047;
          size_t bh = (size_t)bb*8 + hh;
          if (jj == 0) {
            #pragma unroll
            for (int r = 0; r < 4; ++r)
              kbf[(bh*L_ + l + r)*128 + d] = f2bf(acc[mi][ni][r]);
          } else {
            #pragma unroll
            for (int r = 0; r < 4; ++r)
              vtbf[(bh*128 + d)*L_ + l + r] = f2bf(acc[mi][ni][r]);
          }
        }
      }
    }
  }
}

// ---------------- residual + LayerNorm (float4, regs, opt bf16 out) ----------
__global__ __launch_bounds__(256) void resid_ln_k(float* __restrict__ h,
    const float* __restrict__ proj, const float* __restrict__ s, const float* __restrict__ b,
    short* __restrict__ bo) {
  int row = blockIdx.x;
  int tid = threadIdx.x;
  int d = tid*4;
  float* xr = h + (size_t)row*D_;
  const float* pr = proj + (size_t)row*D_;
  __shared__ float red[256];
  float4 xv = *(const float4*)(xr + d);
  float4 pv = *(const float4*)(pr + d);
  float v[4] = { xv.x+pv.x, xv.y+pv.y, xv.z+pv.z, xv.w+pv.w };
  red[tid] = v[0]+v[1]+v[2]+v[3]; __syncthreads();
  for (int st = 128; st > 0; st >>= 1) { if (tid < st) red[tid] += red[tid+st]; __syncthreads(); }
  float mu = red[0] * (1.f/D_); __syncthreads();
  float lv = 0.f;
  #pragma unroll
  for (int j = 0; j < 4; ++j) { float dd = v[j]-mu; lv += dd*dd; }
  red[tid] = lv; __syncthreads();
  for (int st = 128; st > 0; st >>= 1) { if (tid < st) red[tid] += red[tid+st]; __syncthreads(); }
  float var = red[0] * (1.f/D_);
  float r = 1.f/sqrtf(var + EPS_);
  float4 sv = *(const float4*)(s + d);
  float4 bv = *(const float4*)(b + d);
  float4 o;
  o.x = (v[0]-mu)*r*sv.x + bv.x;
  o.y = (v[1]-mu)*r*sv.y + bv.y;
  o.z = (v[2]-mu)*r*sv.z + bv.z;
  o.w = (v[3]-mu)*r*sv.w + bv.w;
  *(float4*)(xr + d) = o;
  if (bo) {
    short4v ob = { f2bf(o.x), f2bf(o.y), f2bf(o.z), f2bf(o.w) };
    *(short4v*)(bo + (size_t)row*D_ + d) = ob;
  }
}

// ---------------- flash attention: bf16 in, swizzled dbuf LDS, prefetch ------
// 1-D grid of 512 blocks, XCD-chunked so each XCD owns 2 (b,h) KV sets.
#define PPITCH 72
__global__ __launch_bounds__(256) void attn2_k(const short* __restrict__ qbf,
    const short* __restrict__ kbf, const short* __restrict__ vtbf,
    short* __restrict__ obf) {
  __shared__ short Ks[2][64*128];   // [kv 64][d 128] swizzled 16B blocks
  __shared__ short Vts[2][128*64];  // [d 128][kv 64] swizzled 16B blocks
  __shared__ short Ps[4*16*PPITCH];

  const int tid  = threadIdx.x;
  const int wave = tid >> 6;
  const int lane = tid & 63;
  const int g    = lane >> 4;
  const int c    = lane & 15;

  int flat = blockIdx.x;                        // 512 blocks
  int swz  = (flat & 7)*64 + (flat >> 3);       // chunk 64/XCD = 2 bh
  const int qt = swz & 31;
  const int hh = (swz >> 5) & 7;
  const int b  = swz >> 8;
  const int q0 = qt*64 + wave*16;
  const size_t bh = (size_t)(b*HEADS_ + hh);

  bf16x8 qf[4];
  {
    const short* Qp = qbf + ((size_t)(b*L_ + q0 + c))*D_ + hh*HD_;
    #pragma unroll
    for (int kd = 0; kd < 4; ++kd)
      qf[kd] = *(const bf16x8*)(Qp + kd*32 + g*8);
  }

  f32x4 O[8];
  #pragma unroll
  for (int i = 0; i < 8; ++i) O[i] = (f32x4){0.f,0.f,0.f,0.f};
  float mrun[4] = {-INFINITY,-INFINITY,-INFINITY,-INFINITY};
  float lrun[4] = {0.f,0.f,0.f,0.f};
  short* Pw = Ps + wave*16*PPITCH;

  const short* kBase = kbf + bh*L_*128;
  const short* vBase = vtbf + bh*128*L_;

  auto stage = [&](int t, int buf) {
    #pragma unroll
    for (int rd = 0; rd < 4; ++rd) {
      int slot = rd*256 + tid;
      int kr = slot >> 4, kj = slot & 15;
      int vr = slot >> 3, vj = slot & 7;
      gld16(kBase + ((size_t)(t*64 + kr))*128 + ((kj ^ (kr & 15)) * 8),
            (char*)&Ks[buf][0] + (rd*256 + wave*64)*16);
      gld16(vBase + (size_t)vr*L_ + t*64 + ((vj ^ (vr & 7)) * 8),
            (char*)&Vts[buf][0] + (rd*256 + wave*64)*16);
    }
  };

  stage(0, 0);
  sync_prefetch();
  int cur = 0;
  const int NT = L_/64;

  for (int t = 0; t < NT; ++t) {
    if (t + 1 < NT) stage(t + 1, cur^1);

    f32x4 s[4];
    #pragma unroll
    for (int nc = 0; nc < 4; ++nc) {
      s[nc] = (f32x4){0.f,0.f,0.f,0.f};
      int R = nc*16 + c;
      #pragma unroll
      for (int kd = 0; kd < 4; ++kd) {
        bf16x8 kf = *(const bf16x8*)&Ks[cur][R*128 + (((kd*4 + g) ^ (R & 15)) * 8)];
        s[nc] = MFMA16(qf[kd], kf, s[nc]);
      }
    }

    float tm[4], rsum[4], alpha[4];
    #pragma unroll
    for (int r = 0; r < 4; ++r)
      tm[r] = fmaxf(fmaxf(s[0][r], s[1][r]), fmaxf(s[2][r], s[3][r]));
    #pragma unroll
    for (int r = 0; r < 4; ++r) {
      #pragma unroll
      for (int mask = 1; mask <= 8; mask <<= 1)
        tm[r] = fmaxf(tm[r], __shfl_xor(tm[r], mask));
      float mnew = fmaxf(mrun[r], tm[r]);
      alpha[r] = expf(mrun[r] - mnew);
      mrun[r] = mnew;
      rsum[r] = 0.f;
    }
    #pragma unroll
    for (int nc = 0; nc < 4; ++nc)
      #pragma unroll
      for (int r = 0; r < 4; ++r) {
        float p = expf(s[nc][r] - mrun[r]);
        s[nc][r] = p;
        rsum[r] += p;
      }
    #pragma unroll
    for (int r = 0; r < 4; ++r) {
      #pragma unroll
      for (int mask = 1; mask <= 8; mask <<= 1)
        rsum[r] += __shfl_xor(rsum[r], mask);
      lrun[r] = lrun[r]*alpha[r] + rsum[r];
    }
    #pragma unroll
    for (int nc = 0; nc < 8; ++nc)
      #pragma unroll
      for (int r = 0; r < 4; ++r) O[nc][r] *= alpha[r];

    #pragma unroll
    for (int nc = 0; nc < 4; ++nc)
      #pragma unroll
      for (int r = 0; r < 4; ++r)
        Pw[(g*4+r)*PPITCH + nc*16 + c] = f2bf(s[nc][r]);
    asm volatile("s_waitcnt lgkmcnt(0)" ::: "memory");
    bf16x8 pa0 = *(const bf16x8*)&Pw[c*PPITCH + g*8];
    bf16x8 pa1 = *(const bf16x8*)&Pw[c*PPITCH + 32 + g*8];

    #pragma unroll
    for (int ks = 0; ks < 2; ++ks) {
      #pragma unroll
      for (int nc = 0; nc < 8; ++nc) {
        int R = nc*16 + c;
        bf16x8 vf = *(const bf16x8*)&Vts[cur][R*64 + (((ks*4 + g) ^ (R & 7)) * 8)];
        O[nc] = MFMA16(ks ? pa1 : pa0, vf, O[nc]);
      }
    }

    if (t + 1 < NT) {
      sync_prefetch();
      cur ^= 1;
    }
  }

  short* ob = obf + ((size_t)(b*L_ + q0))*D_ + hh*HD_;
  #pragma unroll
  for (int r = 0; r < 4; ++r) {
    float inv = 1.f / lrun[r];
    #pragma unroll
    for (int nc = 0; nc < 8; ++nc)
      ob[(size_t)(g*4+r)*D_ + nc*16 + c] = f2bf(O[nc][r] * inv);
  }
}

// ---------------- heads ----------------
__global__ __launch_bounds__(256) void lm_head_part_k(const float* __restrict__ h,
    const float* __restrict__ lm_w, float* __restrict__ part) {
  int tid = threadIdx.x;
  int n = (blockIdx.x*256 + tid)*4;
  int ks = blockIdx.y;
  __shared__ float last0[256], last1[256];
  const float* h0 = h + ((size_t)0*L_ + (L_-1))*D_ + ks*256;
  const float* h1 = h + ((size_t)1*L_ + (L_-1))*D_ + ks*256;
  last0[tid] = h0[tid]; last1[tid] = h1[tid];
  __syncthreads();
  float4 a0 = {0.f,0.f,0.f,0.f}, a1 = {0.f,0.f,0.f,0.f};
  const float* wp = lm_w + (size_t)(ks*256)*VOCAB_ + n;
  for (int kk = 0; kk < 256; ++kk) {
    float4 wv = *(const float4*)(wp + (size_t)kk*VOCAB_);
    float c0 = last0[kk], c1 = last1[kk];
    a0.x += c0*wv.x; a0.y += c0*wv.y; a0.z += c0*wv.z; a0.w += c0*wv.w;
    a1.x += c1*wv.x; a1.y += c1*wv.y; a1.z += c1*wv.z; a1.w += c1*wv.w;
  }
  *(float4*)(part + ((size_t)ks*2 + 0)*VOCAB_ + n) = a0;
  *(float4*)(part + ((size_t)ks*2 + 1)*VOCAB_ + n) = a1;
}

__global__ __launch_bounds__(256) void lm_head_red_k(const float* __restrict__ part,
    float* __restrict__ out) {
  int i = blockIdx.x*256 + threadIdx.x;        // over 2*VOCAB/4 float4s
  int j = (i*4) / VOCAB_;
  int n = (i*4) & (VOCAB_-1);
  float4 acc = {0.f,0.f,0.f,0.f};
  #pragma unroll
  for (int ks = 0; ks < 4; ++ks) {
    float4 v = *(const float4*)(part + ((size_t)ks*2 + j)*VOCAB_ + n);
    acc.x += v.x; acc.y += v.y; acc.z += v.z; acc.w += v.w;
  }
  *(float4*)(out + (size_t)j*VOCAB_ + n) = acc;
}

__global__ __launch_bounds__(128) void tool_head_k(const float* __restrict__ h,
    const float* __restrict__ tw, const float* __restrict__ tb, float* __restrict__ out) {
  int b = blockIdx.x;
  int tid = threadIdx.x;
  __shared__ float last[D_];
  const float* hr = h + ((size_t)b*L_ + (L_-1))*D_;
  for (int d = tid; d < D_; d += 128) last[d] = hr[d];
  __syncthreads();
  float acc = tb[tid];
  for (int k = 0; k < D_; ++k) acc += last[k]*tw[(size_t)k*TOOLV_ + tid];
  out[(size_t)2*VOCAB_ + (size_t)b*TOOLV_ + tid] = acc;
}

extern "C" void kernel_launch(void* const* d_in, const int* in_sizes, int n_in,
                              void* d_out, int out_size, void* d_ws, size_t ws_size,
                              hipStream_t stream) {
  const float* cs        = (const float*)d_in[1];
  const float* proj_w    = (const float*)d_in[2];
  const float* emb_scale = (const float*)d_in[3];
  const float* conv_dw_w = (const float*)d_in[4];
  const float* conv_dw_b = (const float*)d_in[5];
  const float* conv_pw_w = (const float*)d_in[6];
  const float* conv_pw_b = (const float*)d_in[7];
  const float* conv_ln_s = (const float*)d_in[8];
  const float* conv_ln_b = (const float*)d_in[9];
  const float* attn_q_w  = (const float*)d_in[10];
  const float* attn_kv_w = (const float*)d_in[11];
  const float* attn_out_w= (const float*)d_in[12];
  const float* attn_ln_s = (const float*)d_in[13];
  const float* attn_ln_b = (const float*)d_in[14];
  const float* lm_w      = (const float*)d_in[15];
  const float* tool_w    = (const float*)d_in[16];
  const float* tool_b    = (const float*)d_in[17];

  const int M = B_*L_;                              // 4096
  float* h    = (float*)d_ws;                       // M*D fp32
  float* buf2 = h    + (size_t)M*D_;                // M*2D fp32 (lower: proj/glu; upper: qbf)
  short* kbf  = (short*)(buf2 + (size_t)M*2*D_);    // B*H*L*128 bf16
  short* vtbf = kbf + (size_t)B_*HEADS_*L_*128;     // B*H*128*L bf16
  short* abf  = (short*)(vtbf + (size_t)B_*HEADS_*128*L_);  // M*D bf16
  short* wconv= abf + (size_t)M*D_;                 // 10 * 2D*D bf16 (permuted)
  short* wqkv = wconv + (size_t)NCONV_*2*D_*D_;     // 6 * 3D*D bf16
  short* wout = wqkv + (size_t)NATTN_*3*D_*D_;      // 6 * D*D bf16
  float* lmpart = (float*)(wout + (size_t)NATTN_*D_*D_);  // 4*2*VOCAB fp32
  short* qbf  = (short*)(buf2 + (size_t)M*D_);      // M*D bf16 (upper half of buf2)

  const float scale = 0.088388347648318447f;        // 128^-0.5

  // ---- batched weight prep (4 launches) ----
  {
    cvt_perm_k<<<dim3((2*D_*D_/4)/256, NCONV_), 256, 0, stream>>>(conv_pw_w, wconv);
    transp_bf16_k<<<dim3(D_/32, D_/32, NATTN_), 256, 0, stream>>>(
        attn_q_w, wqkv, D_, D_, (size_t)D_*D_, (size_t)3*D_*D_);
    transp_bf16_k<<<dim3((2*D_)/32, D_/32, NATTN_), 256, 0, stream>>>(
        attn_kv_w, wqkv + (size_t)D_*D_, D_, 2*D_, (size_t)D_*2*D_, (size_t)3*D_*D_);
    transp_bf16_k<<<dim3(D_/32, D_/32, NATTN_), 256, 0, stream>>>(
        attn_out_w, wout, D_, D_, (size_t)D_*D_, (size_t)D_*D_);
  }

  julia_proj_k<<<M, 256, 0, stream>>>(cs, proj_w, emb_scale, h);

  for (int i = 0; i < NCONV_; ++i) {
    dwconv_k<<<(M*D_/4)/256, 256, 0, stream>>>(h, conv_dw_w + (size_t)i*D_*5,
                                               conv_dw_b + (size_t)i*D_, abf);
    gemm_bf16<4><<<dim3(M/128, (2*D_)/128), 256, 0, stream>>>(
        abf, wconv + (size_t)i*2*D_*D_, conv_pw_b + (size_t)i*2*D_,
        buf2, nullptr, nullptr, nullptr, 1.f, M, 2*D_, D_);
    resid_ln_k<<<M, 256, 0, stream>>>(h, buf2, conv_ln_s + (size_t)i*D_,
                                      conv_ln_b + (size_t)i*D_,
                                      (i == NCONV_-1) ? abf : (short*)nullptr);
  }

  for (int i = 0; i < NATTN_; ++i) {
    // abf holds bf16(h) from previous LN
    gemm_bf16<3><<<dim3(M/128, (3*D_)/128), 256, 0, stream>>>(
        abf, wqkv + (size_t)i*3*D_*D_, nullptr, nullptr, qbf, kbf, vtbf,
        scale, M, 3*D_, D_);
    attn2_k<<<(L_/64)*HEADS_*B_, 256, 0, stream>>>(qbf, kbf, vtbf, abf);
    gemm_bf16<0><<<dim3(M/128, D_/128), 256, 0, stream>>>(
        abf, wout + (size_t)i*D_*D_, nullptr, buf2, nullptr, nullptr, nullptr,
        1.f, M, D_, D_);
    resid_ln_k<<<M, 256, 0, stream>>>(h, buf2, attn_ln_s + (size_t)i*D_,
                                      attn_ln_b + (size_t)i*D_,
                                      (i < NATTN_-1) ? abf : (short*)nullptr);
  }

  lm_head_part_k<<<dim3(VOCAB_/1024, 4), 256, 0, stream>>>(h, lm_w, lmpart);
  lm_head_red_k<<<(2*VOCAB_/4)/256, 256, 0, stream>>>(lmpart, (float*)d_out);
  tool_head_k<<<B_, 128, 0, stream>>>(h, tool_w, tool_b, (float*)d_out);
}